// Round 3
// baseline (917.343 us; speedup 1.0000x reference)
//
#include <hip/hip_runtime.h>

#define K_FEATS 128
#define SCAN_CHUNK 1024
#define CHUNK 6400    // edges per chunk: 25.6 KB LDS stage, 16B-aligned offsets
#define BPR 8192      // bins per range: 32 KB LDS histogram / cursors
#define MAXCHUNKS 256 // partial arrays (ushort) must fit n*512 B overlay

// ---------------- count: LDS-staged chunk, loop ranges over LDS copy --------
// grid = (nchunks, 2): y=0 -> src (deg_out partials), y=1 -> dst (deg_in partials)
__global__ __launch_bounds__(256) void count_kernel(
    const int* __restrict__ src, const int* __restrict__ dst,
    unsigned short* __restrict__ partial_out, unsigned short* __restrict__ partial_in,
    int ne, int n, int nranges)
{
    __shared__ int eb[CHUNK];
    __shared__ int h[BPR];
    int c = blockIdx.x, a = blockIdx.y;
    const int* idx = a ? dst : src;
    unsigned short* part = a ? partial_in : partial_out;
    int t = threadIdx.x;
    int e0 = c * CHUNK, e1 = min(ne, e0 + CHUNK), len = e1 - e0;
    int len4 = len & ~3;
    for (int i = t * 4; i < len4; i += 1024)
        *(int4*)(eb + i) = *(const int4*)(idx + e0 + i);
    for (int i = len4 + t; i < len; i += 256) eb[i] = idx[e0 + i];
    __syncthreads();
    for (int r = 0; r < nranges; r++) {
        int lo = r * BPR;
        for (int i = t; i < BPR; i += 256) h[i] = 0;
        __syncthreads();
        for (int i = t; i < len; i += 256) {
            int b = eb[i] - lo;
            if ((unsigned)b < (unsigned)BPR) atomicAdd(&h[b], 1);
        }
        __syncthreads();
        for (int i = t; i < BPR; i += 256) {
            int gb = lo + i;
            if (gb < n) part[(size_t)c * n + gb] = (unsigned short)h[i];
        }
        __syncthreads();
    }
}

// ---------------- reduce partials -> degrees, norms; in-place chunk prefix ----
__global__ __launch_bounds__(256) void reduce_prefix(
    unsigned short* __restrict__ partial_in, const unsigned short* __restrict__ partial_out,
    int* __restrict__ deg_in, float* __restrict__ norm_src,
    float* __restrict__ norm_dst, int* __restrict__ row_off,
    int nchunks, int n, int ne)
{
    int i = blockIdx.x * 256 + threadIdx.x;
    if (i == 0) row_off[n] = ne;
    if (i >= n) return;
    int run = 0;
    for (int c = 0; c < nchunks; c++) {
        size_t p = (size_t)c * n + i;
        int v = partial_in[p];
        partial_in[p] = (unsigned short)run;  // exclusive prefix over chunks
        run += v;
    }
    deg_in[i] = run;
    norm_dst[i] = rsqrtf((float)max(run, 1));
    int s = 0;
    for (int c = 0; c < nchunks; c++) s += partial_out[(size_t)c * n + i];
    norm_src[i] = rsqrtf((float)max(s, 1));
}

// ---------------- 3-phase exclusive scan of deg_in -> row_off ----------------
__global__ __launch_bounds__(256) void scan_a(const int* __restrict__ deg,
                                              int* __restrict__ partial, int n)
{
    __shared__ int sh[256];
    int t = threadIdx.x;
    int base = blockIdx.x * SCAN_CHUNK + t * 4;
    int s = 0;
#pragma unroll
    for (int j = 0; j < 4; j++)
        if (base + j < n) s += deg[base + j];
    sh[t] = s;
    __syncthreads();
    for (int off = 128; off > 0; off >>= 1) {
        if (t < off) sh[t] += sh[t + off];
        __syncthreads();
    }
    if (t == 0) partial[blockIdx.x] = sh[0];
}

__global__ void scan_b(int* __restrict__ partial, int nb)
{
    if (threadIdx.x == 0) {
        int run = 0;
        for (int i = 0; i < nb; i++) {
            int v = partial[i];
            partial[i] = run;
            run += v;
        }
    }
}

__global__ __launch_bounds__(256) void scan_c(const int* __restrict__ deg,
                                              const int* __restrict__ partial,
                                              int* __restrict__ row_off, int n)
{
    __shared__ int sh[256];
    int t = threadIdx.x;
    int base = blockIdx.x * SCAN_CHUNK + t * 4;
    int v[4];
    int s = 0;
#pragma unroll
    for (int j = 0; j < 4; j++) {
        v[j] = (base + j < n) ? deg[base + j] : 0;
        s += v[j];
    }
    sh[t] = s;
    __syncthreads();
    for (int off = 1; off < 256; off <<= 1) {
        int x = (t >= off) ? sh[t - off] : 0;
        __syncthreads();
        sh[t] += x;
        __syncthreads();
    }
    int excl = sh[t] - s + partial[blockIdx.x];
#pragma unroll
    for (int j = 0; j < 4; j++) {
        if (base + j < n) row_off[base + j] = excl;
        excl += v[j];
    }
}

// ---------------- CSR fill: dst chunk staged in LDS, cursors per range -------
__global__ __launch_bounds__(256) void scatter_kernel(
    const int* __restrict__ src, const int* __restrict__ dst,
    const int* __restrict__ row_off, const unsigned short* __restrict__ prefix_in,
    int* __restrict__ csr, int ne, int n, int nranges)
{
    __shared__ int ebd[CHUNK];
    __shared__ int cur[BPR];
    int c = blockIdx.x;
    int t = threadIdx.x;
    int e0 = c * CHUNK, e1 = min(ne, e0 + CHUNK), len = e1 - e0;
    int len4 = len & ~3;
    for (int i = t * 4; i < len4; i += 1024)
        *(int4*)(ebd + i) = *(const int4*)(dst + e0 + i);
    for (int i = len4 + t; i < len; i += 256) ebd[i] = dst[e0 + i];
    __syncthreads();
    for (int r = 0; r < nranges; r++) {
        int lo = r * BPR;
        for (int i = t; i < BPR; i += 256) {
            int gb = lo + i;
            cur[i] = (gb < n) ? row_off[gb] + (int)prefix_in[(size_t)c * n + gb] : 0;
        }
        __syncthreads();
        for (int i = t; i < len; i += 256) {
            int d = ebd[i] - lo;
            if ((unsigned)d < (unsigned)BPR) {
                int pos = atomicAdd(&cur[d], 1);
                csr[pos] = src[e0 + i];  // each edge's src fetched exactly once
            }
        }
        __syncthreads();
    }
}

// ---------------- GEMM: T = rowscale ⊙ (X @ W), K=128, M in {128,64} --------
// W staged per-K-slice (16 rows) -> 16.6 KB LDS -> 4+ blocks/CU
template <int M>
__global__ __launch_bounds__(256) void gemm_scale(
    const float* __restrict__ X, const float* __restrict__ W,
    const float* __restrict__ scale, float* __restrict__ T, int n)
{
    constexpr int KC = 16;
    constexpr int CT = M / 8;       // col-threads: 16 (M=128) or 8 (M=64)
    constexpr int RT = 256 / CT;    // row-threads: 16 or 32
    constexpr int RPT = 128 / RT;   // rows per thread: 8 or 4
    constexpr int XPITCH = 132;     // pad: conflict-free reads, 16B-aligned

    __shared__ float Ws[KC * M];
    __shared__ float Xs[KC * XPITCH];

    int t = threadIdx.x;
    int tc = t % CT;
    int tr = t / CT;
    int block_row = blockIdx.x * 128;

    float acc[RPT][8] = {};

    for (int k0 = 0; k0 < K_FEATS; k0 += KC) {
        // stage W K-slice: rows k0..k0+15 are KC*M contiguous floats
        constexpr int WV4 = KC * M / 4;
#pragma unroll
        for (int i = 0; i < WV4 / 256; i++)
            ((float4*)Ws)[t + i * 256] = ((const float4*)(W + k0 * M))[t + i * 256];
        // stage X chunk transposed: Xs[kk][row], 128 rows x KC cols
#pragma unroll
        for (int i = 0; i < (128 * KC) / (256 * 4); i++) {  // 2 float4 per thread
            int idx4 = t + i * 256;       // over [128][KC/4]
            int r = idx4 / (KC / 4);
            int c4 = idx4 % (KC / 4);
            int gr = block_row + r;
            float4 v = make_float4(0.f, 0.f, 0.f, 0.f);
            if (gr < n) v = *(const float4*)(X + (size_t)gr * K_FEATS + k0 + c4 * 4);
            Xs[(c4 * 4 + 0) * XPITCH + r] = v.x;
            Xs[(c4 * 4 + 1) * XPITCH + r] = v.y;
            Xs[(c4 * 4 + 2) * XPITCH + r] = v.z;
            Xs[(c4 * 4 + 3) * XPITCH + r] = v.w;
        }
        __syncthreads();
#pragma unroll 8
        for (int kk = 0; kk < KC; kk++) {
            float4 w0 = *(const float4*)&Ws[kk * M + 8 * tc];
            float4 w1 = *(const float4*)&Ws[kk * M + 8 * tc + 4];
            float xr[RPT];
#pragma unroll
            for (int g = 0; g < RPT / 4; g++) {
                float4 xa = *(const float4*)&Xs[kk * XPITCH + 4 * tr + g * (4 * RT)];
                xr[g * 4 + 0] = xa.x;
                xr[g * 4 + 1] = xa.y;
                xr[g * 4 + 2] = xa.z;
                xr[g * 4 + 3] = xa.w;
            }
#pragma unroll
            for (int i = 0; i < RPT; i++) {
                acc[i][0] += xr[i] * w0.x;
                acc[i][1] += xr[i] * w0.y;
                acc[i][2] += xr[i] * w0.z;
                acc[i][3] += xr[i] * w0.w;
                acc[i][4] += xr[i] * w1.x;
                acc[i][5] += xr[i] * w1.y;
                acc[i][6] += xr[i] * w1.z;
                acc[i][7] += xr[i] * w1.w;
            }
        }
        __syncthreads();
    }

    // epilogue: scale row by norm_src and store
#pragma unroll
    for (int i = 0; i < RPT; i++) {
        int r = block_row + 4 * tr + (i & 3) + (i >> 2) * (4 * RT);
        if (r < n) {
            float s = scale[r];
            float4 o0 = make_float4(acc[i][0] * s, acc[i][1] * s, acc[i][2] * s, acc[i][3] * s);
            float4 o1 = make_float4(acc[i][4] * s, acc[i][5] * s, acc[i][6] * s, acc[i][7] * s);
            *(float4*)(T + (size_t)r * M + 8 * tc) = o0;
            *(float4*)(T + (size_t)r * M + 8 * tc + 4) = o1;
        }
    }
}

// ---------------- aggregation: out[v] = act( ndst[v]*sum_{u in N(v)} T[u] + b ) ----
template <bool RELU>
__global__ __launch_bounds__(256) void aggregate4(
    const float* __restrict__ Tm, const int* __restrict__ row_off,
    const int* __restrict__ csr, const float* __restrict__ ndst,
    const float* __restrict__ bias, float* __restrict__ out, int n)
{
    int lane = threadIdx.x & 31;
    int team = threadIdx.x >> 5;
    int fb = lane * 4;
    float4 b = *(const float4*)(bias + fb);
    int stride = gridDim.x * 8;
    for (int v = blockIdx.x * 8 + team; v < n; v += stride) {
        int s = row_off[v], e = row_off[v + 1];
        float nd = ndst[v];
        float ax = 0.f, ay = 0.f, az = 0.f, aw = 0.f;
        int i = s;
        for (; i + 4 <= e; i += 4) {
            int u0 = csr[i], u1 = csr[i + 1], u2 = csr[i + 2], u3 = csr[i + 3];
            float4 t0 = *(const float4*)(Tm + (size_t)u0 * 128 + fb);
            float4 t1 = *(const float4*)(Tm + (size_t)u1 * 128 + fb);
            float4 t2 = *(const float4*)(Tm + (size_t)u2 * 128 + fb);
            float4 t3 = *(const float4*)(Tm + (size_t)u3 * 128 + fb);
            ax += (t0.x + t1.x) + (t2.x + t3.x);
            ay += (t0.y + t1.y) + (t2.y + t3.y);
            az += (t0.z + t1.z) + (t2.z + t3.z);
            aw += (t0.w + t1.w) + (t2.w + t3.w);
        }
        for (; i < e; i++) {
            int u = csr[i];
            float4 t0 = *(const float4*)(Tm + (size_t)u * 128 + fb);
            ax += t0.x; ay += t0.y; az += t0.z; aw += t0.w;
        }
        float4 o;
        o.x = nd * ax + b.x;
        o.y = nd * ay + b.y;
        o.z = nd * az + b.z;
        o.w = nd * aw + b.w;
        if (RELU) {
            o.x = fmaxf(o.x, 0.f); o.y = fmaxf(o.y, 0.f);
            o.z = fmaxf(o.z, 0.f); o.w = fmaxf(o.w, 0.f);
        }
        *(float4*)(out + (size_t)v * 128 + fb) = o;
    }
}

template <bool RELU>
__global__ __launch_bounds__(256) void aggregate2(
    const float* __restrict__ Tm, const int* __restrict__ row_off,
    const int* __restrict__ csr, const float* __restrict__ ndst,
    const float* __restrict__ bias, float* __restrict__ out, int n)
{
    int lane = threadIdx.x & 31;
    int team = threadIdx.x >> 5;
    int fb = lane * 2;
    float2 b = *(const float2*)(bias + fb);
    int stride = gridDim.x * 8;
    for (int v = blockIdx.x * 8 + team; v < n; v += stride) {
        int s = row_off[v], e = row_off[v + 1];
        float nd = ndst[v];
        float ax = 0.f, ay = 0.f;
        int i = s;
        for (; i + 4 <= e; i += 4) {
            int u0 = csr[i], u1 = csr[i + 1], u2 = csr[i + 2], u3 = csr[i + 3];
            float2 t0 = *(const float2*)(Tm + (size_t)u0 * 64 + fb);
            float2 t1 = *(const float2*)(Tm + (size_t)u1 * 64 + fb);
            float2 t2 = *(const float2*)(Tm + (size_t)u2 * 64 + fb);
            float2 t3 = *(const float2*)(Tm + (size_t)u3 * 64 + fb);
            ax += (t0.x + t1.x) + (t2.x + t3.x);
            ay += (t0.y + t1.y) + (t2.y + t3.y);
        }
        for (; i < e; i++) {
            int u = csr[i];
            float2 t0 = *(const float2*)(Tm + (size_t)u * 64 + fb);
            ax += t0.x; ay += t0.y;
        }
        float2 o;
        o.x = nd * ax + b.x;
        o.y = nd * ay + b.y;
        if (RELU) { o.x = fmaxf(o.x, 0.f); o.y = fmaxf(o.y, 0.f); }
        *(float2*)(out + (size_t)v * 64 + fb) = o;
    }
}

// ---------------- launch ----------------
extern "C" void kernel_launch(void* const* d_in, const int* in_sizes, int n_in,
                              void* d_out, int out_size, void* d_ws, size_t ws_size,
                              hipStream_t stream)
{
    const float* features = (const float*)d_in[0];
    const int* src = (const int*)d_in[1];
    const int* dst = (const int*)d_in[2];
    const float* W0 = (const float*)d_in[3];
    const float* b0 = (const float*)d_in[4];
    const float* W1 = (const float*)d_in[5];
    const float* b1 = (const float*)d_in[6];
    const float* W2 = (const float*)d_in[7];
    const float* b2 = (const float*)d_in[8];

    int n = in_sizes[0] / K_FEATS;  // 100000
    int ne = in_sizes[1];           // 1600000

    char* ws = (char*)d_ws;
    size_t off = 0;
    auto take = [&](size_t bytes) -> char* {
        char* p = ws + off;
        off = (off + bytes + 255) & ~(size_t)255;
        return p;
    };
    float* bufA = (float*)take((size_t)n * 128 * 4);
    float* bufB = (float*)take((size_t)n * 128 * 4);
    int* deg_in = (int*)take((size_t)n * 4);
    int* row_off = (int*)take((size_t)(n + 1) * 4);
    int* partial = (int*)take(1024 * 4);
    float* norm_src = (float*)take((size_t)n * 4);
    float* norm_dst = (float*)take((size_t)n * 4);
    int* csr = (int*)take((size_t)ne * 4);

    // ushort partial histogram arrays overlay bufA/bufB (live only pre-GEMM)
    // size = nchunks * n * 2 B <= n * 512 B  (nchunks <= 256)
    unsigned short* partial_in = (unsigned short*)bufA;
    unsigned short* partial_out = (unsigned short*)bufB;

    int nchunks = (ne + CHUNK - 1) / CHUNK;   // 250
    int nranges = (n + BPR - 1) / BPR;        // 13

    count_kernel<<<dim3(nchunks, 2), 256, 0, stream>>>(
        src, dst, partial_out, partial_in, ne, n, nranges);
    reduce_prefix<<<(n + 255) / 256, 256, 0, stream>>>(
        partial_in, partial_out, deg_in, norm_src, norm_dst, row_off, nchunks, n, ne);
    int nb = (n + SCAN_CHUNK - 1) / SCAN_CHUNK;
    scan_a<<<nb, 256, 0, stream>>>(deg_in, partial, n);
    scan_b<<<1, 64, 0, stream>>>(partial, nb);
    scan_c<<<nb, 256, 0, stream>>>(deg_in, partial, row_off, n);
    scatter_kernel<<<nchunks, 256, 0, stream>>>(
        src, dst, row_off, partial_in, csr, ne, n, nranges);

    int gblocks = (n + 127) / 128;
    int ablocks = (n + 7) / 8;

    // layer 0: T = Nsrc ⊙ (X @ W0); h = relu(Ndst ⊙ A·T + b0)
    gemm_scale<128><<<gblocks, 256, 0, stream>>>(features, W0, norm_src, bufA, n);
    aggregate4<true><<<ablocks, 256, 0, stream>>>(bufA, row_off, csr, norm_dst, b0, bufB, n);
    // layer 1
    gemm_scale<128><<<gblocks, 256, 0, stream>>>(bufB, W1, norm_src, bufA, n);
    aggregate4<true><<<ablocks, 256, 0, stream>>>(bufA, row_off, csr, norm_dst, b1, bufB, n);
    // layer 2 (M=64, no relu) -> d_out
    gemm_scale<64><<<gblocks, 256, 0, stream>>>(bufB, W2, norm_src, bufA, n);
    aggregate2<false><<<ablocks, 256, 0, stream>>>(bufA, row_off, csr, norm_dst, b2,
                                                   (float*)d_out, n);
}

// Round 4
// 624.739 us; speedup vs baseline: 1.4684x; 1.4684x over previous
//
#include <hip/hip_runtime.h>

#define K_FEATS 128
#define SCAN_CHUNK 1024
#define RBSHIFT 9
#define RB 512        // fine-bucket node range (pow2); NB = ceil(n/512) <= 256

// ---------------- coarse count: 256-bin LDS hist per chunk -------------------
// grid (C, 2): y=0 -> src, y=1 -> dst
__global__ __launch_bounds__(256) void bucket_count(
    const int* __restrict__ src, const int* __restrict__ dst,
    int* __restrict__ partialS, int* __restrict__ partialD,
    int ne, int chunkA, int C, int NB)
{
    __shared__ int h[256];
    int c = blockIdx.x, t = threadIdx.x;
    const int* key = blockIdx.y ? dst : src;
    int* part = blockIdx.y ? partialD : partialS;
    if (t < NB) h[t] = 0;
    __syncthreads();
    int e0 = c * chunkA, e1 = min(ne, e0 + chunkA);
    for (int e = e0 + t; e < e1; e += 256)
        atomicAdd(&h[key[e] >> RBSHIFT], 1);
    __syncthreads();
    for (int i = t; i < NB; i += 256) part[i * C + c] = h[i];
}

// ---------------- per-bucket exclusive scan over chunks ----------------------
__global__ __launch_bounds__(256) void bucket_prefix(
    int* __restrict__ partialS, int* __restrict__ partialD,
    int* __restrict__ totS, int* __restrict__ totD, int C, int NB)
{
    __shared__ int sh[256];
    int b = blockIdx.x, t = threadIdx.x;
    int* part = blockIdx.y ? partialD : partialS;
    int* tot = blockIdx.y ? totD : totS;
    int v = (t < C) ? part[b * C + t] : 0;
    sh[t] = v;
    __syncthreads();
    for (int off = 1; off < 256; off <<= 1) {
        int x = (t >= off) ? sh[t - off] : 0;
        __syncthreads();
        sh[t] += x;
        __syncthreads();
    }
    if (t < C) part[b * C + t] = sh[t] - v;
    if (t == 255) tot[b] = sh[255];
}

// ---------------- bucket base offsets (1 block) + row_off sentinel ----------
__global__ __launch_bounds__(256) void bucket_off_kernel(
    const int* __restrict__ totS, const int* __restrict__ totD,
    int* __restrict__ offS, int* __restrict__ offD,
    int* __restrict__ row_off, int NB, int n, int ne)
{
    __shared__ int sh[256];
    int t = threadIdx.x;
    if (t == 0) row_off[n] = ne;
    for (int a = 0; a < 2; a++) {
        const int* tot = a ? totD : totS;
        int* boff = a ? offD : offS;
        int v = (t < NB) ? tot[t] : 0;
        sh[t] = v;
        __syncthreads();
        for (int off = 1; off < 256; off <<= 1) {
            int x = (t >= off) ? sh[t - off] : 0;
            __syncthreads();
            sh[t] += x;
            __syncthreads();
        }
        if (t < NB) boff[t] = sh[t] - v;
        if (t == NB - 1) boff[NB] = sh[t];
        __syncthreads();
    }
}

// ---------------- coarse scatter into buckets (single pass, LDS cursors) ----
__global__ __launch_bounds__(256) void bucket_scatter(
    const int* __restrict__ src, const int* __restrict__ dst,
    const int* __restrict__ partialS, const int* __restrict__ partialD,
    const int* __restrict__ offS, const int* __restrict__ offD,
    int* __restrict__ src_bkt, int2* __restrict__ edge_bkt,
    int ne, int chunkA, int C, int NB)
{
    __shared__ int cur[256];
    int c = blockIdx.x, a = blockIdx.y, t = threadIdx.x;
    const int* part = a ? partialD : partialS;
    const int* boff = a ? offD : offS;
    if (t < NB) cur[t] = boff[t] + part[t * C + c];
    __syncthreads();
    int e0 = c * chunkA, e1 = min(ne, e0 + chunkA);
    if (a) {
        for (int e = e0 + t; e < e1; e += 256) {
            int d = dst[e];
            int pos = atomicAdd(&cur[d >> RBSHIFT], 1);
            edge_bkt[pos] = make_int2(d, src[e]);
        }
    } else {
        for (int e = e0 + t; e < e1; e += 256) {
            int s = src[e];
            int pos = atomicAdd(&cur[s >> RBSHIFT], 1);
            src_bkt[pos] = s;
        }
    }
}

// ---------------- fine counts: per-bucket 512-bin hist -> degrees/norms -----
__global__ __launch_bounds__(256) void fine_count_dst(
    const int2* __restrict__ edge_bkt, const int* __restrict__ offD,
    int* __restrict__ deg_in, float* __restrict__ norm_dst, int n)
{
    __shared__ int h[RB];
    int b = blockIdx.x, t = threadIdx.x;
    for (int i = t; i < RB; i += 256) h[i] = 0;
    __syncthreads();
    int lo = b << RBSHIFT;
    int e1 = offD[b + 1];
    for (int e = offD[b] + t; e < e1; e += 256)
        atomicAdd(&h[edge_bkt[e].x - lo], 1);
    __syncthreads();
    for (int i = t; i < RB; i += 256) {
        int g = lo + i;
        if (g < n) {
            int d = h[i];
            deg_in[g] = d;
            norm_dst[g] = rsqrtf((float)max(d, 1));
        }
    }
}

__global__ __launch_bounds__(256) void fine_count_src(
    const int* __restrict__ src_bkt, const int* __restrict__ offS,
    float* __restrict__ norm_src, int n)
{
    __shared__ int h[RB];
    int b = blockIdx.x, t = threadIdx.x;
    for (int i = t; i < RB; i += 256) h[i] = 0;
    __syncthreads();
    int lo = b << RBSHIFT;
    int e1 = offS[b + 1];
    for (int e = offS[b] + t; e < e1; e += 256)
        atomicAdd(&h[src_bkt[e] - lo], 1);
    __syncthreads();
    for (int i = t; i < RB; i += 256) {
        int g = lo + i;
        if (g < n) norm_src[g] = rsqrtf((float)max(h[i], 1));
    }
}

// ---------------- 3-phase exclusive scan of deg_in -> row_off ----------------
__global__ __launch_bounds__(256) void scan_a(const int* __restrict__ deg,
                                              int* __restrict__ partial, int n)
{
    __shared__ int sh[256];
    int t = threadIdx.x;
    int base = blockIdx.x * SCAN_CHUNK + t * 4;
    int s = 0;
#pragma unroll
    for (int j = 0; j < 4; j++)
        if (base + j < n) s += deg[base + j];
    sh[t] = s;
    __syncthreads();
    for (int off = 128; off > 0; off >>= 1) {
        if (t < off) sh[t] += sh[t + off];
        __syncthreads();
    }
    if (t == 0) partial[blockIdx.x] = sh[0];
}

__global__ void scan_b(int* __restrict__ partial, int nb)
{
    if (threadIdx.x == 0) {
        int run = 0;
        for (int i = 0; i < nb; i++) {
            int v = partial[i];
            partial[i] = run;
            run += v;
        }
    }
}

__global__ __launch_bounds__(256) void scan_c(const int* __restrict__ deg,
                                              const int* __restrict__ partial,
                                              int* __restrict__ row_off, int n)
{
    __shared__ int sh[256];
    int t = threadIdx.x;
    int base = blockIdx.x * SCAN_CHUNK + t * 4;
    int v[4];
    int s = 0;
#pragma unroll
    for (int j = 0; j < 4; j++) {
        v[j] = (base + j < n) ? deg[base + j] : 0;
        s += v[j];
    }
    sh[t] = s;
    __syncthreads();
    for (int off = 1; off < 256; off <<= 1) {
        int x = (t >= off) ? sh[t - off] : 0;
        __syncthreads();
        sh[t] += x;
        __syncthreads();
    }
    int excl = sh[t] - s + partial[blockIdx.x];
#pragma unroll
    for (int j = 0; j < 4; j++) {
        if (base + j < n) row_off[base + j] = excl;
        excl += v[j];
    }
}

// ---------------- fine scatter: per-bucket cursors = row_off -----------------
__global__ __launch_bounds__(256) void fine_scatter(
    const int2* __restrict__ edge_bkt, const int* __restrict__ offD,
    const int* __restrict__ row_off, int* __restrict__ csr, int n)
{
    __shared__ int cur[RB];
    int b = blockIdx.x, t = threadIdx.x;
    int lo = b << RBSHIFT;
    for (int i = t; i < RB; i += 256) {
        int g = lo + i;
        cur[i] = (g < n) ? row_off[g] : 0;
    }
    __syncthreads();
    int e1 = offD[b + 1];
    for (int e = offD[b] + t; e < e1; e += 256) {
        int2 p = edge_bkt[e];
        int pos = atomicAdd(&cur[p.x - lo], 1);
        csr[pos] = p.y;
    }
}

// ---------------- GEMM: T = rowscale ⊙ (X @ W), K=128, M in {128,64} --------
template <int M>
__global__ __launch_bounds__(256) void gemm_scale(
    const float* __restrict__ X, const float* __restrict__ W,
    const float* __restrict__ scale, float* __restrict__ T, int n)
{
    constexpr int KC = 16;
    constexpr int CT = M / 8;
    constexpr int RT = 256 / CT;
    constexpr int RPT = 128 / RT;
    constexpr int XPITCH = 132;

    __shared__ float Ws[KC * M];
    __shared__ float Xs[KC * XPITCH];

    int t = threadIdx.x;
    int tc = t % CT;
    int tr = t / CT;
    int block_row = blockIdx.x * 128;

    float acc[RPT][8] = {};

    for (int k0 = 0; k0 < K_FEATS; k0 += KC) {
        constexpr int WV4 = KC * M / 4;
#pragma unroll
        for (int i = 0; i < WV4 / 256; i++)
            ((float4*)Ws)[t + i * 256] = ((const float4*)(W + k0 * M))[t + i * 256];
#pragma unroll
        for (int i = 0; i < (128 * KC) / (256 * 4); i++) {
            int idx4 = t + i * 256;
            int r = idx4 / (KC / 4);
            int c4 = idx4 % (KC / 4);
            int gr = block_row + r;
            float4 v = make_float4(0.f, 0.f, 0.f, 0.f);
            if (gr < n) v = *(const float4*)(X + (size_t)gr * K_FEATS + k0 + c4 * 4);
            Xs[(c4 * 4 + 0) * XPITCH + r] = v.x;
            Xs[(c4 * 4 + 1) * XPITCH + r] = v.y;
            Xs[(c4 * 4 + 2) * XPITCH + r] = v.z;
            Xs[(c4 * 4 + 3) * XPITCH + r] = v.w;
        }
        __syncthreads();
#pragma unroll 8
        for (int kk = 0; kk < KC; kk++) {
            float4 w0 = *(const float4*)&Ws[kk * M + 8 * tc];
            float4 w1 = *(const float4*)&Ws[kk * M + 8 * tc + 4];
            float xr[RPT];
#pragma unroll
            for (int g = 0; g < RPT / 4; g++) {
                float4 xa = *(const float4*)&Xs[kk * XPITCH + 4 * tr + g * (4 * RT)];
                xr[g * 4 + 0] = xa.x;
                xr[g * 4 + 1] = xa.y;
                xr[g * 4 + 2] = xa.z;
                xr[g * 4 + 3] = xa.w;
            }
#pragma unroll
            for (int i = 0; i < RPT; i++) {
                acc[i][0] += xr[i] * w0.x;
                acc[i][1] += xr[i] * w0.y;
                acc[i][2] += xr[i] * w0.z;
                acc[i][3] += xr[i] * w0.w;
                acc[i][4] += xr[i] * w1.x;
                acc[i][5] += xr[i] * w1.y;
                acc[i][6] += xr[i] * w1.z;
                acc[i][7] += xr[i] * w1.w;
            }
        }
        __syncthreads();
    }

#pragma unroll
    for (int i = 0; i < RPT; i++) {
        int r = block_row + 4 * tr + (i & 3) + (i >> 2) * (4 * RT);
        if (r < n) {
            float s = scale[r];
            float4 o0 = make_float4(acc[i][0] * s, acc[i][1] * s, acc[i][2] * s, acc[i][3] * s);
            float4 o1 = make_float4(acc[i][4] * s, acc[i][5] * s, acc[i][6] * s, acc[i][7] * s);
            *(float4*)(T + (size_t)r * M + 8 * tc) = o0;
            *(float4*)(T + (size_t)r * M + 8 * tc + 4) = o1;
        }
    }
}

// ---------------- aggregation ------------------------------------------------
template <bool RELU>
__global__ __launch_bounds__(256) void aggregate4(
    const float* __restrict__ Tm, const int* __restrict__ row_off,
    const int* __restrict__ csr, const float* __restrict__ ndst,
    const float* __restrict__ bias, float* __restrict__ out, int n)
{
    int lane = threadIdx.x & 31;
    int team = threadIdx.x >> 5;
    int fb = lane * 4;
    float4 b = *(const float4*)(bias + fb);
    int stride = gridDim.x * 8;
    for (int v = blockIdx.x * 8 + team; v < n; v += stride) {
        int s = row_off[v], e = row_off[v + 1];
        float nd = ndst[v];
        float ax = 0.f, ay = 0.f, az = 0.f, aw = 0.f;
        int i = s;
        for (; i + 4 <= e; i += 4) {
            int u0 = csr[i], u1 = csr[i + 1], u2 = csr[i + 2], u3 = csr[i + 3];
            float4 t0 = *(const float4*)(Tm + (size_t)u0 * 128 + fb);
            float4 t1 = *(const float4*)(Tm + (size_t)u1 * 128 + fb);
            float4 t2 = *(const float4*)(Tm + (size_t)u2 * 128 + fb);
            float4 t3 = *(const float4*)(Tm + (size_t)u3 * 128 + fb);
            ax += (t0.x + t1.x) + (t2.x + t3.x);
            ay += (t0.y + t1.y) + (t2.y + t3.y);
            az += (t0.z + t1.z) + (t2.z + t3.z);
            aw += (t0.w + t1.w) + (t2.w + t3.w);
        }
        for (; i < e; i++) {
            int u = csr[i];
            float4 t0 = *(const float4*)(Tm + (size_t)u * 128 + fb);
            ax += t0.x; ay += t0.y; az += t0.z; aw += t0.w;
        }
        float4 o;
        o.x = nd * ax + b.x;
        o.y = nd * ay + b.y;
        o.z = nd * az + b.z;
        o.w = nd * aw + b.w;
        if (RELU) {
            o.x = fmaxf(o.x, 0.f); o.y = fmaxf(o.y, 0.f);
            o.z = fmaxf(o.z, 0.f); o.w = fmaxf(o.w, 0.f);
        }
        *(float4*)(out + (size_t)v * 128 + fb) = o;
    }
}

template <bool RELU>
__global__ __launch_bounds__(256) void aggregate2(
    const float* __restrict__ Tm, const int* __restrict__ row_off,
    const int* __restrict__ csr, const float* __restrict__ ndst,
    const float* __restrict__ bias, float* __restrict__ out, int n)
{
    int lane = threadIdx.x & 31;
    int team = threadIdx.x >> 5;
    int fb = lane * 2;
    float2 b = *(const float2*)(bias + fb);
    int stride = gridDim.x * 8;
    for (int v = blockIdx.x * 8 + team; v < n; v += stride) {
        int s = row_off[v], e = row_off[v + 1];
        float nd = ndst[v];
        float ax = 0.f, ay = 0.f;
        int i = s;
        for (; i + 4 <= e; i += 4) {
            int u0 = csr[i], u1 = csr[i + 1], u2 = csr[i + 2], u3 = csr[i + 3];
            float2 t0 = *(const float2*)(Tm + (size_t)u0 * 64 + fb);
            float2 t1 = *(const float2*)(Tm + (size_t)u1 * 64 + fb);
            float2 t2 = *(const float2*)(Tm + (size_t)u2 * 64 + fb);
            float2 t3 = *(const float2*)(Tm + (size_t)u3 * 64 + fb);
            ax += (t0.x + t1.x) + (t2.x + t3.x);
            ay += (t0.y + t1.y) + (t2.y + t3.y);
        }
        for (; i < e; i++) {
            int u = csr[i];
            float2 t0 = *(const float2*)(Tm + (size_t)u * 64 + fb);
            ax += t0.x; ay += t0.y;
        }
        float2 o;
        o.x = nd * ax + b.x;
        o.y = nd * ay + b.y;
        if (RELU) { o.x = fmaxf(o.x, 0.f); o.y = fmaxf(o.y, 0.f); }
        *(float2*)(out + (size_t)v * 64 + fb) = o;
    }
}

// ---------------- launch ----------------
extern "C" void kernel_launch(void* const* d_in, const int* in_sizes, int n_in,
                              void* d_out, int out_size, void* d_ws, size_t ws_size,
                              hipStream_t stream)
{
    const float* features = (const float*)d_in[0];
    const int* src = (const int*)d_in[1];
    const int* dst = (const int*)d_in[2];
    const float* W0 = (const float*)d_in[3];
    const float* b0 = (const float*)d_in[4];
    const float* W1 = (const float*)d_in[5];
    const float* b1 = (const float*)d_in[6];
    const float* W2 = (const float*)d_in[7];
    const float* b2 = (const float*)d_in[8];

    int n = in_sizes[0] / K_FEATS;  // 100000
    int ne = in_sizes[1];           // 1600000

    char* ws = (char*)d_ws;
    size_t off = 0;
    auto take = [&](size_t bytes) -> char* {
        char* p = ws + off;
        off = (off + bytes + 255) & ~(size_t)255;
        return p;
    };
    float* bufA = (float*)take((size_t)n * 128 * 4);
    float* bufB = (float*)take((size_t)n * 128 * 4);
    int* deg_in = (int*)take((size_t)n * 4);
    int* row_off = (int*)take((size_t)(n + 1) * 4);
    int* partial = (int*)take(1024 * 4);
    float* norm_src = (float*)take((size_t)n * 4);
    float* norm_dst = (float*)take((size_t)n * 4);
    int* csr = (int*)take((size_t)ne * 4);

    int NB = (n + RB - 1) >> RBSHIFT;        // 196 (must be <= 256)
    int chunkA = 8192;
    int C = (ne + chunkA - 1) / chunkA;
    if (C > 256) { chunkA = (ne + 255) / 256; C = (ne + chunkA - 1) / chunkA; }

    int* partialS = (int*)take((size_t)NB * C * 4);
    int* partialD = (int*)take((size_t)NB * C * 4);
    int* totS = (int*)take((size_t)NB * 4);
    int* totD = (int*)take((size_t)NB * 4);
    int* offS = (int*)take((size_t)(NB + 1) * 4);
    int* offD = (int*)take((size_t)(NB + 1) * 4);

    // bucket-sorted arrays overlay bufA/bufB (live only pre-GEMM)
    int2* edge_bkt = (int2*)bufA;   // ne * 8 B = 12.8 MB < 51.2 MB
    int* src_bkt = (int*)bufB;      // ne * 4 B

    bucket_count<<<dim3(C, 2), 256, 0, stream>>>(src, dst, partialS, partialD,
                                                 ne, chunkA, C, NB);
    bucket_prefix<<<dim3(NB, 2), 256, 0, stream>>>(partialS, partialD, totS, totD, C, NB);
    bucket_off_kernel<<<1, 256, 0, stream>>>(totS, totD, offS, offD, row_off, NB, n, ne);
    bucket_scatter<<<dim3(C, 2), 256, 0, stream>>>(src, dst, partialS, partialD,
                                                   offS, offD, src_bkt, edge_bkt,
                                                   ne, chunkA, C, NB);
    fine_count_dst<<<NB, 256, 0, stream>>>(edge_bkt, offD, deg_in, norm_dst, n);
    fine_count_src<<<NB, 256, 0, stream>>>(src_bkt, offS, norm_src, n);
    int nb = (n + SCAN_CHUNK - 1) / SCAN_CHUNK;
    scan_a<<<nb, 256, 0, stream>>>(deg_in, partial, n);
    scan_b<<<1, 64, 0, stream>>>(partial, nb);
    scan_c<<<nb, 256, 0, stream>>>(deg_in, partial, row_off, n);
    fine_scatter<<<NB, 256, 0, stream>>>(edge_bkt, offD, row_off, csr, n);

    int gblocks = (n + 127) / 128;
    int ablocks = (n + 7) / 8;

    // layer 0: T = Nsrc ⊙ (X @ W0); h = relu(Ndst ⊙ A·T + b0)
    gemm_scale<128><<<gblocks, 256, 0, stream>>>(features, W0, norm_src, bufA, n);
    aggregate4<true><<<ablocks, 256, 0, stream>>>(bufA, row_off, csr, norm_dst, b0, bufB, n);
    // layer 1
    gemm_scale<128><<<gblocks, 256, 0, stream>>>(bufB, W1, norm_src, bufA, n);
    aggregate4<true><<<ablocks, 256, 0, stream>>>(bufA, row_off, csr, norm_dst, b1, bufB, n);
    // layer 2 (M=64, no relu) -> d_out
    gemm_scale<64><<<gblocks, 256, 0, stream>>>(bufB, W2, norm_src, bufA, n);
    aggregate2<false><<<ablocks, 256, 0, stream>>>(bufA, row_off, csr, norm_dst, b2,
                                                   (float*)d_out, n);
}

// Round 5
// 519.410 us; speedup vs baseline: 1.7661x; 1.2028x over previous
//
#include <hip/hip_runtime.h>
#include <hip/hip_fp16.h>

#define K_FEATS 128
#define SCAN_CHUNK 1024
#define RBSHIFT 9
#define RB 512        // fine-bucket node range (pow2); NB = ceil(n/512) <= 256

// ---------------- coarse count: 256-bin LDS hist per chunk -------------------
// grid (C, 2): y=0 -> src, y=1 -> dst
__global__ __launch_bounds__(256) void bucket_count(
    const int* __restrict__ src, const int* __restrict__ dst,
    int* __restrict__ partialS, int* __restrict__ partialD,
    int ne, int chunkA, int C, int NB)
{
    __shared__ int h[256];
    int c = blockIdx.x, t = threadIdx.x;
    const int* key = blockIdx.y ? dst : src;
    int* part = blockIdx.y ? partialD : partialS;
    if (t < NB) h[t] = 0;
    __syncthreads();
    int e0 = c * chunkA, e1 = min(ne, e0 + chunkA);
    for (int e = e0 + t; e < e1; e += 256)
        atomicAdd(&h[key[e] >> RBSHIFT], 1);
    __syncthreads();
    for (int i = t; i < NB; i += 256) part[i * C + c] = h[i];
}

// ---------------- per-bucket exclusive scan over chunks ----------------------
__global__ __launch_bounds__(256) void bucket_prefix(
    int* __restrict__ partialS, int* __restrict__ partialD,
    int* __restrict__ totS, int* __restrict__ totD, int C, int NB)
{
    __shared__ int sh[256];
    int b = blockIdx.x, t = threadIdx.x;
    int* part = blockIdx.y ? partialD : partialS;
    int* tot = blockIdx.y ? totD : totS;
    int v = (t < C) ? part[b * C + t] : 0;
    sh[t] = v;
    __syncthreads();
    for (int off = 1; off < 256; off <<= 1) {
        int x = (t >= off) ? sh[t - off] : 0;
        __syncthreads();
        sh[t] += x;
        __syncthreads();
    }
    if (t < C) part[b * C + t] = sh[t] - v;
    if (t == 255) tot[b] = sh[255];
}

// ---------------- bucket base offsets (1 block) + row_off sentinel ----------
__global__ __launch_bounds__(256) void bucket_off_kernel(
    const int* __restrict__ totS, const int* __restrict__ totD,
    int* __restrict__ offS, int* __restrict__ offD,
    int* __restrict__ row_off, int NB, int n, int ne)
{
    __shared__ int sh[256];
    int t = threadIdx.x;
    if (t == 0) row_off[n] = ne;
    for (int a = 0; a < 2; a++) {
        const int* tot = a ? totD : totS;
        int* boff = a ? offD : offS;
        int v = (t < NB) ? tot[t] : 0;
        sh[t] = v;
        __syncthreads();
        for (int off = 1; off < 256; off <<= 1) {
            int x = (t >= off) ? sh[t - off] : 0;
            __syncthreads();
            sh[t] += x;
            __syncthreads();
        }
        if (t < NB) boff[t] = sh[t] - v;
        if (t == NB - 1) boff[NB] = sh[t];
        __syncthreads();
    }
}

// ---------------- coarse scatter into buckets (single pass, LDS cursors) ----
__global__ __launch_bounds__(256) void bucket_scatter(
    const int* __restrict__ src, const int* __restrict__ dst,
    const int* __restrict__ partialS, const int* __restrict__ partialD,
    const int* __restrict__ offS, const int* __restrict__ offD,
    int* __restrict__ src_bkt, int2* __restrict__ edge_bkt,
    int ne, int chunkA, int C, int NB)
{
    __shared__ int cur[256];
    int c = blockIdx.x, a = blockIdx.y, t = threadIdx.x;
    const int* part = a ? partialD : partialS;
    const int* boff = a ? offD : offS;
    if (t < NB) cur[t] = boff[t] + part[t * C + c];
    __syncthreads();
    int e0 = c * chunkA, e1 = min(ne, e0 + chunkA);
    if (a) {
        for (int e = e0 + t; e < e1; e += 256) {
            int d = dst[e];
            int pos = atomicAdd(&cur[d >> RBSHIFT], 1);
            edge_bkt[pos] = make_int2(d, src[e]);
        }
    } else {
        for (int e = e0 + t; e < e1; e += 256) {
            int s = src[e];
            int pos = atomicAdd(&cur[s >> RBSHIFT], 1);
            src_bkt[pos] = s;
        }
    }
}

// ---------------- fine counts: per-bucket 512-bin hist -> degrees/norms -----
__global__ __launch_bounds__(256) void fine_count_dst(
    const int2* __restrict__ edge_bkt, const int* __restrict__ offD,
    int* __restrict__ deg_in, float* __restrict__ norm_dst, int n)
{
    __shared__ int h[RB];
    int b = blockIdx.x, t = threadIdx.x;
    for (int i = t; i < RB; i += 256) h[i] = 0;
    __syncthreads();
    int lo = b << RBSHIFT;
    int e1 = offD[b + 1];
    for (int e = offD[b] + t; e < e1; e += 256)
        atomicAdd(&h[edge_bkt[e].x - lo], 1);
    __syncthreads();
    for (int i = t; i < RB; i += 256) {
        int g = lo + i;
        if (g < n) {
            int d = h[i];
            deg_in[g] = d;
            norm_dst[g] = rsqrtf((float)max(d, 1));
        }
    }
}

__global__ __launch_bounds__(256) void fine_count_src(
    const int* __restrict__ src_bkt, const int* __restrict__ offS,
    float* __restrict__ norm_src, int n)
{
    __shared__ int h[RB];
    int b = blockIdx.x, t = threadIdx.x;
    for (int i = t; i < RB; i += 256) h[i] = 0;
    __syncthreads();
    int lo = b << RBSHIFT;
    int e1 = offS[b + 1];
    for (int e = offS[b] + t; e < e1; e += 256)
        atomicAdd(&h[src_bkt[e] - lo], 1);
    __syncthreads();
    for (int i = t; i < RB; i += 256) {
        int g = lo + i;
        if (g < n) norm_src[g] = rsqrtf((float)max(h[i], 1));
    }
}

// ---------------- 3-phase exclusive scan of deg_in -> row_off ----------------
__global__ __launch_bounds__(256) void scan_a(const int* __restrict__ deg,
                                              int* __restrict__ partial, int n)
{
    __shared__ int sh[256];
    int t = threadIdx.x;
    int base = blockIdx.x * SCAN_CHUNK + t * 4;
    int s = 0;
#pragma unroll
    for (int j = 0; j < 4; j++)
        if (base + j < n) s += deg[base + j];
    sh[t] = s;
    __syncthreads();
    for (int off = 128; off > 0; off >>= 1) {
        if (t < off) sh[t] += sh[t + off];
        __syncthreads();
    }
    if (t == 0) partial[blockIdx.x] = sh[0];
}

__global__ void scan_b(int* __restrict__ partial, int nb)
{
    if (threadIdx.x == 0) {
        int run = 0;
        for (int i = 0; i < nb; i++) {
            int v = partial[i];
            partial[i] = run;
            run += v;
        }
    }
}

__global__ __launch_bounds__(256) void scan_c(const int* __restrict__ deg,
                                              const int* __restrict__ partial,
                                              int* __restrict__ row_off, int n)
{
    __shared__ int sh[256];
    int t = threadIdx.x;
    int base = blockIdx.x * SCAN_CHUNK + t * 4;
    int v[4];
    int s = 0;
#pragma unroll
    for (int j = 0; j < 4; j++) {
        v[j] = (base + j < n) ? deg[base + j] : 0;
        s += v[j];
    }
    sh[t] = s;
    __syncthreads();
    for (int off = 1; off < 256; off <<= 1) {
        int x = (t >= off) ? sh[t - off] : 0;
        __syncthreads();
        sh[t] += x;
        __syncthreads();
    }
    int excl = sh[t] - s + partial[blockIdx.x];
#pragma unroll
    for (int j = 0; j < 4; j++) {
        if (base + j < n) row_off[base + j] = excl;
        excl += v[j];
    }
}

// ---------------- fine scatter: per-bucket cursors = row_off -----------------
__global__ __launch_bounds__(256) void fine_scatter(
    const int2* __restrict__ edge_bkt, const int* __restrict__ offD,
    const int* __restrict__ row_off, int* __restrict__ csr, int n)
{
    __shared__ int cur[RB];
    int b = blockIdx.x, t = threadIdx.x;
    int lo = b << RBSHIFT;
    for (int i = t; i < RB; i += 256) {
        int g = lo + i;
        cur[i] = (g < n) ? row_off[g] : 0;
    }
    __syncthreads();
    int e1 = offD[b + 1];
    for (int e = offD[b] + t; e < e1; e += 256) {
        int2 p = edge_bkt[e];
        int pos = atomicAdd(&cur[p.x - lo], 1);
        csr[pos] = p.y;
    }
}

// ---------------- GEMM (fp32 out): T = rowscale ⊙ (X @ W) -------------------
template <int M>
__global__ __launch_bounds__(256) void gemm_scale(
    const float* __restrict__ X, const float* __restrict__ W,
    const float* __restrict__ scale, float* __restrict__ T, int n)
{
    constexpr int KC = 16;
    constexpr int CT = M / 8;
    constexpr int RT = 256 / CT;
    constexpr int RPT = 128 / RT;
    constexpr int XPITCH = 132;

    __shared__ float Ws[KC * M];
    __shared__ float Xs[KC * XPITCH];

    int t = threadIdx.x;
    int tc = t % CT;
    int tr = t / CT;
    int block_row = blockIdx.x * 128;

    float acc[RPT][8] = {};

    for (int k0 = 0; k0 < K_FEATS; k0 += KC) {
        constexpr int WV4 = KC * M / 4;
#pragma unroll
        for (int i = 0; i < WV4 / 256; i++)
            ((float4*)Ws)[t + i * 256] = ((const float4*)(W + k0 * M))[t + i * 256];
#pragma unroll
        for (int i = 0; i < (128 * KC) / (256 * 4); i++) {
            int idx4 = t + i * 256;
            int r = idx4 / (KC / 4);
            int c4 = idx4 % (KC / 4);
            int gr = block_row + r;
            float4 v = make_float4(0.f, 0.f, 0.f, 0.f);
            if (gr < n) v = *(const float4*)(X + (size_t)gr * K_FEATS + k0 + c4 * 4);
            Xs[(c4 * 4 + 0) * XPITCH + r] = v.x;
            Xs[(c4 * 4 + 1) * XPITCH + r] = v.y;
            Xs[(c4 * 4 + 2) * XPITCH + r] = v.z;
            Xs[(c4 * 4 + 3) * XPITCH + r] = v.w;
        }
        __syncthreads();
#pragma unroll 8
        for (int kk = 0; kk < KC; kk++) {
            float4 w0 = *(const float4*)&Ws[kk * M + 8 * tc];
            float4 w1 = *(const float4*)&Ws[kk * M + 8 * tc + 4];
            float xr[RPT];
#pragma unroll
            for (int g = 0; g < RPT / 4; g++) {
                float4 xa = *(const float4*)&Xs[kk * XPITCH + 4 * tr + g * (4 * RT)];
                xr[g * 4 + 0] = xa.x;
                xr[g * 4 + 1] = xa.y;
                xr[g * 4 + 2] = xa.z;
                xr[g * 4 + 3] = xa.w;
            }
#pragma unroll
            for (int i = 0; i < RPT; i++) {
                acc[i][0] += xr[i] * w0.x;
                acc[i][1] += xr[i] * w0.y;
                acc[i][2] += xr[i] * w0.z;
                acc[i][3] += xr[i] * w0.w;
                acc[i][4] += xr[i] * w1.x;
                acc[i][5] += xr[i] * w1.y;
                acc[i][6] += xr[i] * w1.z;
                acc[i][7] += xr[i] * w1.w;
            }
        }
        __syncthreads();
    }

#pragma unroll
    for (int i = 0; i < RPT; i++) {
        int r = block_row + 4 * tr + (i & 3) + (i >> 2) * (4 * RT);
        if (r < n) {
            float s = scale[r];
            float4 o0 = make_float4(acc[i][0] * s, acc[i][1] * s, acc[i][2] * s, acc[i][3] * s);
            float4 o1 = make_float4(acc[i][4] * s, acc[i][5] * s, acc[i][6] * s, acc[i][7] * s);
            *(float4*)(T + (size_t)r * M + 8 * tc) = o0;
            *(float4*)(T + (size_t)r * M + 8 * tc + 4) = o1;
        }
    }
}

// ---------------- GEMM with fp16 output (M=128): Th = half(rowscale ⊙ X@W) --
__global__ __launch_bounds__(256) void gemm_scale_h(
    const float* __restrict__ X, const float* __restrict__ W,
    const float* __restrict__ scale, __half* __restrict__ Th, int n)
{
    constexpr int M = 128;
    constexpr int KC = 16;
    constexpr int CT = M / 8;       // 16
    constexpr int RT = 256 / CT;    // 16
    constexpr int RPT = 128 / RT;   // 8
    constexpr int XPITCH = 132;

    __shared__ float Ws[KC * M];
    __shared__ float Xs[KC * XPITCH];

    int t = threadIdx.x;
    int tc = t % CT;
    int tr = t / CT;
    int block_row = blockIdx.x * 128;

    float acc[RPT][8] = {};

    for (int k0 = 0; k0 < K_FEATS; k0 += KC) {
        constexpr int WV4 = KC * M / 4;
#pragma unroll
        for (int i = 0; i < WV4 / 256; i++)
            ((float4*)Ws)[t + i * 256] = ((const float4*)(W + k0 * M))[t + i * 256];
#pragma unroll
        for (int i = 0; i < (128 * KC) / (256 * 4); i++) {
            int idx4 = t + i * 256;
            int r = idx4 / (KC / 4);
            int c4 = idx4 % (KC / 4);
            int gr = block_row + r;
            float4 v = make_float4(0.f, 0.f, 0.f, 0.f);
            if (gr < n) v = *(const float4*)(X + (size_t)gr * K_FEATS + k0 + c4 * 4);
            Xs[(c4 * 4 + 0) * XPITCH + r] = v.x;
            Xs[(c4 * 4 + 1) * XPITCH + r] = v.y;
            Xs[(c4 * 4 + 2) * XPITCH + r] = v.z;
            Xs[(c4 * 4 + 3) * XPITCH + r] = v.w;
        }
        __syncthreads();
#pragma unroll 8
        for (int kk = 0; kk < KC; kk++) {
            float4 w0 = *(const float4*)&Ws[kk * M + 8 * tc];
            float4 w1 = *(const float4*)&Ws[kk * M + 8 * tc + 4];
            float xr[RPT];
#pragma unroll
            for (int g = 0; g < RPT / 4; g++) {
                float4 xa = *(const float4*)&Xs[kk * XPITCH + 4 * tr + g * (4 * RT)];
                xr[g * 4 + 0] = xa.x;
                xr[g * 4 + 1] = xa.y;
                xr[g * 4 + 2] = xa.z;
                xr[g * 4 + 3] = xa.w;
            }
#pragma unroll
            for (int i = 0; i < RPT; i++) {
                acc[i][0] += xr[i] * w0.x;
                acc[i][1] += xr[i] * w0.y;
                acc[i][2] += xr[i] * w0.z;
                acc[i][3] += xr[i] * w0.w;
                acc[i][4] += xr[i] * w1.x;
                acc[i][5] += xr[i] * w1.y;
                acc[i][6] += xr[i] * w1.z;
                acc[i][7] += xr[i] * w1.w;
            }
        }
        __syncthreads();
    }

#pragma unroll
    for (int i = 0; i < RPT; i++) {
        int r = block_row + 4 * tr + (i & 3) + (i >> 2) * (4 * RT);
        if (r < n) {
            float s = scale[r];
            union { uint4 q; __half h[8]; } U;
#pragma unroll
            for (int j = 0; j < 8; j++) U.h[j] = __float2half(acc[i][j] * s);
            *(uint4*)(Th + (size_t)r * M + 8 * tc) = U.q;
        }
    }
}

// ---------------- fp16-gather aggregation (128 feats), fp32 accumulate ------
// 16-lane teams, 8 fp16 feats (16 B) per lane
template <bool RELU>
__global__ __launch_bounds__(256) void aggregate4h(
    const __half* __restrict__ Tm, const int* __restrict__ row_off,
    const int* __restrict__ csr, const float* __restrict__ ndst,
    const float* __restrict__ bias, float* __restrict__ out, int n)
{
    int lane = threadIdx.x & 15;
    int team = threadIdx.x >> 4;
    int fb = lane * 8;
    float b[8];
    *(float4*)&b[0] = *(const float4*)(bias + fb);
    *(float4*)&b[4] = *(const float4*)(bias + fb + 4);
    int stride = gridDim.x * 16;
    for (int v = blockIdx.x * 16 + team; v < n; v += stride) {
        int s = row_off[v], e = row_off[v + 1];
        float nd = ndst[v];
        float a[8] = {};
        int i = s;
        for (; i + 4 <= e; i += 4) {
            int u0 = csr[i], u1 = csr[i + 1], u2 = csr[i + 2], u3 = csr[i + 3];
            union { uint4 q; __half h[8]; } U0, U1, U2, U3;
            U0.q = *(const uint4*)(Tm + (size_t)u0 * 128 + fb);
            U1.q = *(const uint4*)(Tm + (size_t)u1 * 128 + fb);
            U2.q = *(const uint4*)(Tm + (size_t)u2 * 128 + fb);
            U3.q = *(const uint4*)(Tm + (size_t)u3 * 128 + fb);
#pragma unroll
            for (int j = 0; j < 8; j++)
                a[j] += (__half2float(U0.h[j]) + __half2float(U1.h[j])) +
                        (__half2float(U2.h[j]) + __half2float(U3.h[j]));
        }
        for (; i < e; i++) {
            int u = csr[i];
            union { uint4 q; __half h[8]; } U;
            U.q = *(const uint4*)(Tm + (size_t)u * 128 + fb);
#pragma unroll
            for (int j = 0; j < 8; j++) a[j] += __half2float(U.h[j]);
        }
        float o[8];
#pragma unroll
        for (int j = 0; j < 8; j++) {
            o[j] = nd * a[j] + b[j];
            if (RELU) o[j] = fmaxf(o[j], 0.f);
        }
        *(float4*)(out + (size_t)v * 128 + fb) = *(float4*)&o[0];
        *(float4*)(out + (size_t)v * 128 + fb + 4) = *(float4*)&o[4];
    }
}

// ---------------- fp32 aggregation (64 feats) for final layer ----------------
template <bool RELU>
__global__ __launch_bounds__(256) void aggregate2(
    const float* __restrict__ Tm, const int* __restrict__ row_off,
    const int* __restrict__ csr, const float* __restrict__ ndst,
    const float* __restrict__ bias, float* __restrict__ out, int n)
{
    int lane = threadIdx.x & 31;
    int team = threadIdx.x >> 5;
    int fb = lane * 2;
    float2 b = *(const float2*)(bias + fb);
    int stride = gridDim.x * 8;
    for (int v = blockIdx.x * 8 + team; v < n; v += stride) {
        int s = row_off[v], e = row_off[v + 1];
        float nd = ndst[v];
        float ax = 0.f, ay = 0.f;
        int i = s;
        for (; i + 4 <= e; i += 4) {
            int u0 = csr[i], u1 = csr[i + 1], u2 = csr[i + 2], u3 = csr[i + 3];
            float2 t0 = *(const float2*)(Tm + (size_t)u0 * 64 + fb);
            float2 t1 = *(const float2*)(Tm + (size_t)u1 * 64 + fb);
            float2 t2 = *(const float2*)(Tm + (size_t)u2 * 64 + fb);
            float2 t3 = *(const float2*)(Tm + (size_t)u3 * 64 + fb);
            ax += (t0.x + t1.x) + (t2.x + t3.x);
            ay += (t0.y + t1.y) + (t2.y + t3.y);
        }
        for (; i < e; i++) {
            int u = csr[i];
            float2 t0 = *(const float2*)(Tm + (size_t)u * 64 + fb);
            ax += t0.x; ay += t0.y;
        }
        float2 o;
        o.x = nd * ax + b.x;
        o.y = nd * ay + b.y;
        if (RELU) { o.x = fmaxf(o.x, 0.f); o.y = fmaxf(o.y, 0.f); }
        *(float2*)(out + (size_t)v * 64 + fb) = o;
    }
}

// ---------------- launch ----------------
extern "C" void kernel_launch(void* const* d_in, const int* in_sizes, int n_in,
                              void* d_out, int out_size, void* d_ws, size_t ws_size,
                              hipStream_t stream)
{
    const float* features = (const float*)d_in[0];
    const int* src = (const int*)d_in[1];
    const int* dst = (const int*)d_in[2];
    const float* W0 = (const float*)d_in[3];
    const float* b0 = (const float*)d_in[4];
    const float* W1 = (const float*)d_in[5];
    const float* b1 = (const float*)d_in[6];
    const float* W2 = (const float*)d_in[7];
    const float* b2 = (const float*)d_in[8];

    int n = in_sizes[0] / K_FEATS;  // 100000
    int ne = in_sizes[1];           // 1600000

    char* ws = (char*)d_ws;
    size_t off = 0;
    auto take = [&](size_t bytes) -> char* {
        char* p = ws + off;
        off = (off + bytes + 255) & ~(size_t)255;
        return p;
    };
    float* bufA = (float*)take((size_t)n * 128 * 4);
    float* bufB = (float*)take((size_t)n * 128 * 4);
    int* deg_in = (int*)take((size_t)n * 4);
    int* row_off = (int*)take((size_t)(n + 1) * 4);
    int* partial = (int*)take(1024 * 4);
    float* norm_src = (float*)take((size_t)n * 4);
    float* norm_dst = (float*)take((size_t)n * 4);
    int* csr = (int*)take((size_t)ne * 4);

    int NB = (n + RB - 1) >> RBSHIFT;        // 196 (must be <= 256)
    int chunkA = 8192;
    int C = (ne + chunkA - 1) / chunkA;
    if (C > 256) { chunkA = (ne + 255) / 256; C = (ne + chunkA - 1) / chunkA; }

    int* partialS = (int*)take((size_t)NB * C * 4);
    int* partialD = (int*)take((size_t)NB * C * 4);
    int* totS = (int*)take((size_t)NB * 4);
    int* totD = (int*)take((size_t)NB * 4);
    int* offS = (int*)take((size_t)(NB + 1) * 4);
    int* offD = (int*)take((size_t)(NB + 1) * 4);

    // bucket-sorted arrays overlay bufA/bufB (live only pre-GEMM)
    int2* edge_bkt = (int2*)bufA;   // ne * 8 B = 12.8 MB < 51.2 MB
    int* src_bkt = (int*)bufB;      // ne * 4 B

    bucket_count<<<dim3(C, 2), 256, 0, stream>>>(src, dst, partialS, partialD,
                                                 ne, chunkA, C, NB);
    bucket_prefix<<<dim3(NB, 2), 256, 0, stream>>>(partialS, partialD, totS, totD, C, NB);
    bucket_off_kernel<<<1, 256, 0, stream>>>(totS, totD, offS, offD, row_off, NB, n, ne);
    bucket_scatter<<<dim3(C, 2), 256, 0, stream>>>(src, dst, partialS, partialD,
                                                   offS, offD, src_bkt, edge_bkt,
                                                   ne, chunkA, C, NB);
    fine_count_dst<<<NB, 256, 0, stream>>>(edge_bkt, offD, deg_in, norm_dst, n);
    fine_count_src<<<NB, 256, 0, stream>>>(src_bkt, offS, norm_src, n);
    int nb = (n + SCAN_CHUNK - 1) / SCAN_CHUNK;
    scan_a<<<nb, 256, 0, stream>>>(deg_in, partial, n);
    scan_b<<<1, 64, 0, stream>>>(partial, nb);
    scan_c<<<nb, 256, 0, stream>>>(deg_in, partial, row_off, n);
    fine_scatter<<<NB, 256, 0, stream>>>(edge_bkt, offD, row_off, csr, n);

    int gblocks = (n + 127) / 128;
    int ablocks4 = (n + 15) / 16;
    int ablocks2 = (n + 7) / 8;

    __half* Th = (__half*)bufA;     // n*128*2 = 25.6 MB, overlays bufA

    // layer 0: Th = half(Nsrc ⊙ (X @ W0)); h0 = relu(Ndst ⊙ A·Th + b0) -> bufB
    gemm_scale_h<<<gblocks, 256, 0, stream>>>(features, W0, norm_src, Th, n);
    aggregate4h<true><<<ablocks4, 256, 0, stream>>>(Th, row_off, csr, norm_dst, b0, bufB, n);
    // layer 1: Th = half(Nsrc ⊙ (h0 @ W1)); h1 -> bufB (h0 consumed by gemm)
    gemm_scale_h<<<gblocks, 256, 0, stream>>>(bufB, W1, norm_src, Th, n);
    aggregate4h<true><<<ablocks4, 256, 0, stream>>>(Th, row_off, csr, norm_dst, b1, bufB, n);
    // layer 2 (M=64, fp32, no relu) -> d_out
    gemm_scale<64><<<gblocks, 256, 0, stream>>>(bufB, W2, norm_src, bufA, n);
    aggregate2<false><<<ablocks2, 256, 0, stream>>>(bufA, row_off, csr, norm_dst, b2,
                                                    (float*)d_out, n);
}

// Round 6
// 517.233 us; speedup vs baseline: 1.7736x; 1.0042x over previous
//
#include <hip/hip_runtime.h>
#include <hip/hip_fp16.h>

#define K_FEATS 128
#define SCAN_CHUNK 1024
#define RBSHIFT 9
#define RB 512        // fine-bucket node range (pow2); NB = ceil(n/512) <= 256

typedef short bf16x8 __attribute__((ext_vector_type(8)));
typedef float f32x4 __attribute__((ext_vector_type(4)));

__device__ __forceinline__ unsigned short bf16_rne(float x) {
    unsigned u = __float_as_uint(x);
    unsigned r = (u + 0x7FFFu + ((u >> 16) & 1u)) >> 16;
    return (unsigned short)r;
}
__device__ __forceinline__ float bf16_f(unsigned short h) {
    return __uint_as_float(((unsigned)h) << 16);
}

// ---------------- prep: split features into bf16 hi/lo ----------------------
__global__ __launch_bounds__(256) void split_feat(
    const float* __restrict__ X, unsigned short* __restrict__ Xh,
    unsigned short* __restrict__ Xl, int n, int n_pad)
{
    size_t idx = ((size_t)blockIdx.x * 256 + threadIdx.x) * 4;
    if (idx >= (size_t)n_pad * K_FEATS) return;
    int row = (int)(idx >> 7);
    float4 v = make_float4(0.f, 0.f, 0.f, 0.f);
    if (row < n) v = *(const float4*)(X + idx);
    float f[4] = {v.x, v.y, v.z, v.w};
    union { ushort4 q; unsigned short u[4]; } H, L;
#pragma unroll
    for (int j = 0; j < 4; j++) {
        H.u[j] = bf16_rne(f[j]);
        L.u[j] = bf16_rne(f[j] - bf16_f(H.u[j]));
    }
    *(ushort4*)(Xh + idx) = H.q;
    *(ushort4*)(Xl + idx) = L.q;
}

// ---------------- prep: transpose+split W [128][NC] -> Wt hi/lo [NC][128] ---
__global__ __launch_bounds__(256) void split_w(
    const float* __restrict__ W, unsigned short* __restrict__ Wth,
    unsigned short* __restrict__ Wtl, int NC)
{
    int e = blockIdx.x * 256 + threadIdx.x;
    if (e >= NC * K_FEATS) return;
    int c = e >> 7, k = e & 127;
    float w = W[k * NC + c];
    unsigned short h = bf16_rne(w);
    Wth[e] = h;
    Wtl[e] = bf16_rne(w - bf16_f(h));
}

// ---------------- coarse count: 256-bin LDS hist per chunk -------------------
__global__ __launch_bounds__(256) void bucket_count(
    const int* __restrict__ src, const int* __restrict__ dst,
    int* __restrict__ partialS, int* __restrict__ partialD,
    int ne, int chunkA, int C, int NB)
{
    __shared__ int h[256];
    int c = blockIdx.x, t = threadIdx.x;
    const int* key = blockIdx.y ? dst : src;
    int* part = blockIdx.y ? partialD : partialS;
    if (t < NB) h[t] = 0;
    __syncthreads();
    int e0 = c * chunkA, e1 = min(ne, e0 + chunkA);
    for (int e = e0 + t; e < e1; e += 256)
        atomicAdd(&h[key[e] >> RBSHIFT], 1);
    __syncthreads();
    for (int i = t; i < NB; i += 256) part[i * C + c] = h[i];
}

__global__ __launch_bounds__(256) void bucket_prefix(
    int* __restrict__ partialS, int* __restrict__ partialD,
    int* __restrict__ totS, int* __restrict__ totD, int C, int NB)
{
    __shared__ int sh[256];
    int b = blockIdx.x, t = threadIdx.x;
    int* part = blockIdx.y ? partialD : partialS;
    int* tot = blockIdx.y ? totD : totS;
    int v = (t < C) ? part[b * C + t] : 0;
    sh[t] = v;
    __syncthreads();
    for (int off = 1; off < 256; off <<= 1) {
        int x = (t >= off) ? sh[t - off] : 0;
        __syncthreads();
        sh[t] += x;
        __syncthreads();
    }
    if (t < C) part[b * C + t] = sh[t] - v;
    if (t == 255) tot[b] = sh[255];
}

__global__ __launch_bounds__(256) void bucket_off_kernel(
    const int* __restrict__ totS, const int* __restrict__ totD,
    int* __restrict__ offS, int* __restrict__ offD,
    int* __restrict__ row_off, int NB, int n, int ne)
{
    __shared__ int sh[256];
    int t = threadIdx.x;
    if (t == 0) row_off[n] = ne;
    for (int a = 0; a < 2; a++) {
        const int* tot = a ? totD : totS;
        int* boff = a ? offD : offS;
        int v = (t < NB) ? tot[t] : 0;
        sh[t] = v;
        __syncthreads();
        for (int off = 1; off < 256; off <<= 1) {
            int x = (t >= off) ? sh[t - off] : 0;
            __syncthreads();
            sh[t] += x;
            __syncthreads();
        }
        if (t < NB) boff[t] = sh[t] - v;
        if (t == NB - 1) boff[NB] = sh[t];
        __syncthreads();
    }
}

__global__ __launch_bounds__(256) void bucket_scatter(
    const int* __restrict__ src, const int* __restrict__ dst,
    const int* __restrict__ partialS, const int* __restrict__ partialD,
    const int* __restrict__ offS, const int* __restrict__ offD,
    int* __restrict__ src_bkt, int2* __restrict__ edge_bkt,
    int ne, int chunkA, int C, int NB)
{
    __shared__ int cur[256];
    int c = blockIdx.x, a = blockIdx.y, t = threadIdx.x;
    const int* part = a ? partialD : partialS;
    const int* boff = a ? offD : offS;
    if (t < NB) cur[t] = boff[t] + part[t * C + c];
    __syncthreads();
    int e0 = c * chunkA, e1 = min(ne, e0 + chunkA);
    if (a) {
        for (int e = e0 + t; e < e1; e += 256) {
            int d = dst[e];
            int pos = atomicAdd(&cur[d >> RBSHIFT], 1);
            edge_bkt[pos] = make_int2(d, src[e]);
        }
    } else {
        for (int e = e0 + t; e < e1; e += 256) {
            int s = src[e];
            int pos = atomicAdd(&cur[s >> RBSHIFT], 1);
            src_bkt[pos] = s;
        }
    }
}

__global__ __launch_bounds__(256) void fine_count_dst(
    const int2* __restrict__ edge_bkt, const int* __restrict__ offD,
    int* __restrict__ deg_in, float* __restrict__ norm_dst, int n)
{
    __shared__ int h[RB];
    int b = blockIdx.x, t = threadIdx.x;
    for (int i = t; i < RB; i += 256) h[i] = 0;
    __syncthreads();
    int lo = b << RBSHIFT;
    int e1 = offD[b + 1];
    for (int e = offD[b] + t; e < e1; e += 256)
        atomicAdd(&h[edge_bkt[e].x - lo], 1);
    __syncthreads();
    for (int i = t; i < RB; i += 256) {
        int g = lo + i;
        if (g < n) {
            int d = h[i];
            deg_in[g] = d;
            norm_dst[g] = rsqrtf((float)max(d, 1));
        }
    }
}

__global__ __launch_bounds__(256) void fine_count_src(
    const int* __restrict__ src_bkt, const int* __restrict__ offS,
    float* __restrict__ norm_src, int n)
{
    __shared__ int h[RB];
    int b = blockIdx.x, t = threadIdx.x;
    for (int i = t; i < RB; i += 256) h[i] = 0;
    __syncthreads();
    int lo = b << RBSHIFT;
    int e1 = offS[b + 1];
    for (int e = offS[b] + t; e < e1; e += 256)
        atomicAdd(&h[src_bkt[e] - lo], 1);
    __syncthreads();
    for (int i = t; i < RB; i += 256) {
        int g = lo + i;
        if (g < n) norm_src[g] = rsqrtf((float)max(h[i], 1));
    }
}

__global__ __launch_bounds__(256) void scan_a(const int* __restrict__ deg,
                                              int* __restrict__ partial, int n)
{
    __shared__ int sh[256];
    int t = threadIdx.x;
    int base = blockIdx.x * SCAN_CHUNK + t * 4;
    int s = 0;
#pragma unroll
    for (int j = 0; j < 4; j++)
        if (base + j < n) s += deg[base + j];
    sh[t] = s;
    __syncthreads();
    for (int off = 128; off > 0; off >>= 1) {
        if (t < off) sh[t] += sh[t + off];
        __syncthreads();
    }
    if (t == 0) partial[blockIdx.x] = sh[0];
}

__global__ void scan_b(int* __restrict__ partial, int nb)
{
    if (threadIdx.x == 0) {
        int run = 0;
        for (int i = 0; i < nb; i++) {
            int v = partial[i];
            partial[i] = run;
            run += v;
        }
    }
}

__global__ __launch_bounds__(256) void scan_c(const int* __restrict__ deg,
                                              const int* __restrict__ partial,
                                              int* __restrict__ row_off, int n)
{
    __shared__ int sh[256];
    int t = threadIdx.x;
    int base = blockIdx.x * SCAN_CHUNK + t * 4;
    int v[4];
    int s = 0;
#pragma unroll
    for (int j = 0; j < 4; j++) {
        v[j] = (base + j < n) ? deg[base + j] : 0;
        s += v[j];
    }
    sh[t] = s;
    __syncthreads();
    for (int off = 1; off < 256; off <<= 1) {
        int x = (t >= off) ? sh[t - off] : 0;
        __syncthreads();
        sh[t] += x;
        __syncthreads();
    }
    int excl = sh[t] - s + partial[blockIdx.x];
#pragma unroll
    for (int j = 0; j < 4; j++) {
        if (base + j < n) row_off[base + j] = excl;
        excl += v[j];
    }
}

__global__ __launch_bounds__(256) void fine_scatter(
    const int2* __restrict__ edge_bkt, const int* __restrict__ offD,
    const int* __restrict__ row_off, int* __restrict__ csr, int n)
{
    __shared__ int cur[RB];
    int b = blockIdx.x, t = threadIdx.x;
    int lo = b << RBSHIFT;
    for (int i = t; i < RB; i += 256) {
        int g = lo + i;
        cur[i] = (g < n) ? row_off[g] : 0;
    }
    __syncthreads();
    int e1 = offD[b + 1];
    for (int e = offD[b] + t; e < e1; e += 256) {
        int2 p = edge_bkt[e];
        int pos = atomicAdd(&cur[p.x - lo], 1);
        csr[pos] = p.y;
    }
}

// ---------------- MFMA GEMM: out = scale ⊙ (X @ W), bf16 hi/lo split --------
// X as hi/lo bf16 [n_pad][128] row-major; W as hi/lo bf16 TRANSPOSED [NCOL][128].
// block = 4 waves; wave tile = 32 rows x NCOL cols; no LDS.
// A-frag: A[m=lane&15][k=quad*8+j]; B-frag: B[k=quad*8+j][n=lane&15];
// C/D:    col = lane&15, row = quad*4 + reg   (m89/m120-verified layouts)
template <int NCOL, bool HALF_OUT>
__global__ __launch_bounds__(256) void gemm_mfma(
    const unsigned short* __restrict__ Xh, const unsigned short* __restrict__ Xl,
    const unsigned short* __restrict__ Wth, const unsigned short* __restrict__ Wtl,
    const float* __restrict__ scale, void* __restrict__ outv, int n)
{
    constexpr int CT = NCOL / 16;
    int w = threadIdx.x >> 6;
    int lane = threadIdx.x & 63;
    int m = lane & 15;
    int q = lane >> 4;
    int r0 = blockIdx.x * 128 + w * 32;

    f32x4 acc[2][CT];
#pragma unroll
    for (int i = 0; i < 2; i++)
#pragma unroll
        for (int j = 0; j < CT; j++) acc[i][j] = (f32x4){0.f, 0.f, 0.f, 0.f};

    size_t aoff0 = (size_t)(r0 + m) * K_FEATS + q * 8;
    size_t aoff1 = aoff0 + (size_t)16 * K_FEATS;

    for (int k0 = 0; k0 < K_FEATS; k0 += 32) {
        bf16x8 a0h = *(const bf16x8*)(Xh + aoff0 + k0);
        bf16x8 a0l = *(const bf16x8*)(Xl + aoff0 + k0);
        bf16x8 a1h = *(const bf16x8*)(Xh + aoff1 + k0);
        bf16x8 a1l = *(const bf16x8*)(Xl + aoff1 + k0);
#pragma unroll
        for (int ct = 0; ct < CT; ct++) {
            size_t boff = (size_t)(ct * 16 + m) * K_FEATS + q * 8 + k0;
            bf16x8 bh = *(const bf16x8*)(Wth + boff);
            bf16x8 bl = *(const bf16x8*)(Wtl + boff);
            acc[0][ct] = __builtin_amdgcn_mfma_f32_16x16x32_bf16(a0h, bh, acc[0][ct], 0, 0, 0);
            acc[0][ct] = __builtin_amdgcn_mfma_f32_16x16x32_bf16(a0l, bh, acc[0][ct], 0, 0, 0);
            acc[0][ct] = __builtin_amdgcn_mfma_f32_16x16x32_bf16(a0h, bl, acc[0][ct], 0, 0, 0);
            acc[1][ct] = __builtin_amdgcn_mfma_f32_16x16x32_bf16(a1h, bh, acc[1][ct], 0, 0, 0);
            acc[1][ct] = __builtin_amdgcn_mfma_f32_16x16x32_bf16(a1l, bh, acc[1][ct], 0, 0, 0);
            acc[1][ct] = __builtin_amdgcn_mfma_f32_16x16x32_bf16(a1h, bl, acc[1][ct], 0, 0, 0);
        }
    }

#pragma unroll
    for (int rt = 0; rt < 2; rt++) {
        int rb = r0 + rt * 16 + q * 4;
#pragma unroll
        for (int reg = 0; reg < 4; reg++) {
            int row = rb + reg;
            if (row < n) {
                float s = scale[row];
#pragma unroll
                for (int ct = 0; ct < CT; ct++) {
                    float v = acc[rt][ct][reg] * s;
                    size_t o = (size_t)row * NCOL + ct * 16 + m;
                    if (HALF_OUT) ((__half*)outv)[o] = __float2half(v);
                    else ((float*)outv)[o] = v;
                }
            }
        }
    }
}

// ---------------- fp16-gather aggregation (128 feats) -> bf16 hi/lo out -----
// 16-lane teams, 8 fp16 feats (16 B) per lane; fp32 accumulate
template <bool RELU>
__global__ __launch_bounds__(256) void aggregate4h(
    const __half* __restrict__ Tm, const int* __restrict__ row_off,
    const int* __restrict__ csr, const float* __restrict__ ndst,
    const float* __restrict__ bias, unsigned short* __restrict__ Oh,
    unsigned short* __restrict__ Ol, int n)
{
    int lane = threadIdx.x & 15;
    int team = threadIdx.x >> 4;
    int fb = lane * 8;
    float b[8];
    *(float4*)&b[0] = *(const float4*)(bias + fb);
    *(float4*)&b[4] = *(const float4*)(bias + fb + 4);
    int stride = gridDim.x * 16;
    for (int v = blockIdx.x * 16 + team; v < n; v += stride) {
        int s = row_off[v], e = row_off[v + 1];
        float nd = ndst[v];
        float a[8] = {};
        int i = s;
        for (; i + 4 <= e; i += 4) {
            int u0 = csr[i], u1 = csr[i + 1], u2 = csr[i + 2], u3 = csr[i + 3];
            union { uint4 q; __half h[8]; } U0, U1, U2, U3;
            U0.q = *(const uint4*)(Tm + (size_t)u0 * 128 + fb);
            U1.q = *(const uint4*)(Tm + (size_t)u1 * 128 + fb);
            U2.q = *(const uint4*)(Tm + (size_t)u2 * 128 + fb);
            U3.q = *(const uint4*)(Tm + (size_t)u3 * 128 + fb);
#pragma unroll
            for (int j = 0; j < 8; j++)
                a[j] += (__half2float(U0.h[j]) + __half2float(U1.h[j])) +
                        (__half2float(U2.h[j]) + __half2float(U3.h[j]));
        }
        for (; i < e; i++) {
            int u = csr[i];
            union { uint4 q; __half h[8]; } U;
            U.q = *(const uint4*)(Tm + (size_t)u * 128 + fb);
#pragma unroll
            for (int j = 0; j < 8; j++) a[j] += __half2float(U.h[j]);
        }
        union { uint4 q; unsigned short u[8]; } H, L;
#pragma unroll
        for (int j = 0; j < 8; j++) {
            float o = nd * a[j] + b[j];
            if (RELU) o = fmaxf(o, 0.f);
            H.u[j] = bf16_rne(o);
            L.u[j] = bf16_rne(o - bf16_f(H.u[j]));
        }
        *(uint4*)(Oh + (size_t)v * 128 + fb) = H.q;
        *(uint4*)(Ol + (size_t)v * 128 + fb) = L.q;
    }
}

// ---------------- fp32 aggregation (64 feats) for final layer ----------------
template <bool RELU>
__global__ __launch_bounds__(256) void aggregate2(
    const float* __restrict__ Tm, const int* __restrict__ row_off,
    const int* __restrict__ csr, const float* __restrict__ ndst,
    const float* __restrict__ bias, float* __restrict__ out, int n)
{
    int lane = threadIdx.x & 31;
    int team = threadIdx.x >> 5;
    int fb = lane * 2;
    float2 b = *(const float2*)(bias + fb);
    int stride = gridDim.x * 8;
    for (int v = blockIdx.x * 8 + team; v < n; v += stride) {
        int s = row_off[v], e = row_off[v + 1];
        float nd = ndst[v];
        float ax = 0.f, ay = 0.f;
        int i = s;
        for (; i + 4 <= e; i += 4) {
            int u0 = csr[i], u1 = csr[i + 1], u2 = csr[i + 2], u3 = csr[i + 3];
            float2 t0 = *(const float2*)(Tm + (size_t)u0 * 64 + fb);
            float2 t1 = *(const float2*)(Tm + (size_t)u1 * 64 + fb);
            float2 t2 = *(const float2*)(Tm + (size_t)u2 * 64 + fb);
            float2 t3 = *(const float2*)(Tm + (size_t)u3 * 64 + fb);
            ax += (t0.x + t1.x) + (t2.x + t3.x);
            ay += (t0.y + t1.y) + (t2.y + t3.y);
        }
        for (; i < e; i++) {
            int u = csr[i];
            float2 t0 = *(const float2*)(Tm + (size_t)u * 64 + fb);
            ax += t0.x; ay += t0.y;
        }
        float2 o;
        o.x = nd * ax + b.x;
        o.y = nd * ay + b.y;
        if (RELU) { o.x = fmaxf(o.x, 0.f); o.y = fmaxf(o.y, 0.f); }
        *(float2*)(out + (size_t)v * 64 + fb) = o;
    }
}

// ---------------- launch ----------------
extern "C" void kernel_launch(void* const* d_in, const int* in_sizes, int n_in,
                              void* d_out, int out_size, void* d_ws, size_t ws_size,
                              hipStream_t stream)
{
    const float* features = (const float*)d_in[0];
    const int* src = (const int*)d_in[1];
    const int* dst = (const int*)d_in[2];
    const float* W0 = (const float*)d_in[3];
    const float* b0 = (const float*)d_in[4];
    const float* W1 = (const float*)d_in[5];
    const float* b1 = (const float*)d_in[6];
    const float* W2 = (const float*)d_in[7];
    const float* b2 = (const float*)d_in[8];

    int n = in_sizes[0] / K_FEATS;  // 100000
    int ne = in_sizes[1];           // 1600000
    int n_pad = (n + 127) & ~127;   // 100096

    char* ws = (char*)d_ws;
    size_t off = 0;
    auto take = [&](size_t bytes) -> char* {
        char* p = ws + off;
        off = (off + bytes + 255) & ~(size_t)255;
        return p;
    };
    unsigned short* XBh = (unsigned short*)take((size_t)n_pad * 128 * 2);
    unsigned short* XBl = (unsigned short*)take((size_t)n_pad * 128 * 2);
    char* Tbuf = take((size_t)n_pad * 128 * 2);   // fp16 [n][128] or fp32 [n][64]
    int* csr = (int*)take((size_t)ne * 4);
    int2* edge_bkt = (int2*)take((size_t)ne * 8);
    int* src_bkt = (int*)take((size_t)ne * 4);
    int* deg_in = (int*)take((size_t)n * 4);
    int* row_off = (int*)take((size_t)(n + 1) * 4);
    int* partial = (int*)take(1024 * 4);
    float* norm_src = (float*)take((size_t)n * 4);
    float* norm_dst = (float*)take((size_t)n * 4);
    unsigned short* W0th = (unsigned short*)take(128 * 128 * 2);
    unsigned short* W0tl = (unsigned short*)take(128 * 128 * 2);
    unsigned short* W1th = (unsigned short*)take(128 * 128 * 2);
    unsigned short* W1tl = (unsigned short*)take(128 * 128 * 2);
    unsigned short* W2th = (unsigned short*)take(64 * 128 * 2);
    unsigned short* W2tl = (unsigned short*)take(64 * 128 * 2);

    int NB = (n + RB - 1) >> RBSHIFT;        // 196 (must be <= 256)
    int chunkA = 8192;
    int C = (ne + chunkA - 1) / chunkA;
    if (C > 256) { chunkA = (ne + 255) / 256; C = (ne + chunkA - 1) / chunkA; }

    int* partialS = (int*)take((size_t)NB * C * 4);
    int* partialD = (int*)take((size_t)NB * C * 4);
    int* totS = (int*)take((size_t)NB * 4);
    int* totD = (int*)take((size_t)NB * 4);
    int* offS = (int*)take((size_t)(NB + 1) * 4);
    int* offD = (int*)take((size_t)(NB + 1) * 4);

    // prep: feature + weight splits
    int fblocks = (int)(((size_t)n_pad * 128 / 4 + 255) / 256);
    split_feat<<<fblocks, 256, 0, stream>>>(features, XBh, XBl, n, n_pad);
    split_w<<<64, 256, 0, stream>>>(W0, W0th, W0tl, 128);
    split_w<<<64, 256, 0, stream>>>(W1, W1th, W1tl, 128);
    split_w<<<32, 256, 0, stream>>>(W2, W2th, W2tl, 64);

    // CSR build (two-level counting sort)
    bucket_count<<<dim3(C, 2), 256, 0, stream>>>(src, dst, partialS, partialD,
                                                 ne, chunkA, C, NB);
    bucket_prefix<<<dim3(NB, 2), 256, 0, stream>>>(partialS, partialD, totS, totD, C, NB);
    bucket_off_kernel<<<1, 256, 0, stream>>>(totS, totD, offS, offD, row_off, NB, n, ne);
    bucket_scatter<<<dim3(C, 2), 256, 0, stream>>>(src, dst, partialS, partialD,
                                                   offS, offD, src_bkt, edge_bkt,
                                                   ne, chunkA, C, NB);
    fine_count_dst<<<NB, 256, 0, stream>>>(edge_bkt, offD, deg_in, norm_dst, n);
    fine_count_src<<<NB, 256, 0, stream>>>(src_bkt, offS, norm_src, n);
    int nb = (n + SCAN_CHUNK - 1) / SCAN_CHUNK;
    scan_a<<<nb, 256, 0, stream>>>(deg_in, partial, n);
    scan_b<<<1, 64, 0, stream>>>(partial, nb);
    scan_c<<<nb, 256, 0, stream>>>(deg_in, partial, row_off, n);
    fine_scatter<<<NB, 256, 0, stream>>>(edge_bkt, offD, row_off, csr, n);

    int gblocks = n_pad / 128;
    int ablocks4 = (n + 15) / 16;
    int ablocks2 = (n + 7) / 8;
    __half* Th = (__half*)Tbuf;
    float* T64 = (float*)Tbuf;

    // layer 0
    gemm_mfma<128, true><<<gblocks, 256, 0, stream>>>(XBh, XBl, W0th, W0tl,
                                                      norm_src, Th, n);
    aggregate4h<true><<<ablocks4, 256, 0, stream>>>(Th, row_off, csr, norm_dst, b0,
                                                    XBh, XBl, n);
    // layer 1 (in-place ping: gemm consumed XB before agg rewrites it)
    gemm_mfma<128, true><<<gblocks, 256, 0, stream>>>(XBh, XBl, W1th, W1tl,
                                                      norm_src, Th, n);
    aggregate4h<true><<<ablocks4, 256, 0, stream>>>(Th, row_off, csr, norm_dst, b1,
                                                    XBh, XBl, n);
    // layer 2 (NCOL=64, fp32 out, no relu)
    gemm_mfma<64, false><<<gblocks, 256, 0, stream>>>(XBh, XBl, W2th, W2tl,
                                                      norm_src, T64, n);
    aggregate2<false><<<ablocks2, 256, 0, stream>>>(T64, row_off, csr, norm_dst, b2,
                                                    (float*)d_out, n);
}

// Round 7
// 467.761 us; speedup vs baseline: 1.9611x; 1.1058x over previous
//
#include <hip/hip_runtime.h>
#include <hip/hip_fp16.h>

#define K_FEATS 128
#define RBSHIFT 9
#define RB 512        // fine-bucket node range (pow2); NB = ceil(n/512) <= 256

typedef short bf16x8 __attribute__((ext_vector_type(8)));
typedef float f32x4 __attribute__((ext_vector_type(4)));

__device__ __forceinline__ unsigned short bf16_rne(float x) {
    unsigned u = __float_as_uint(x);
    unsigned r = (u + 0x7FFFu + ((u >> 16) & 1u)) >> 16;
    return (unsigned short)r;
}
__device__ __forceinline__ float bf16_f(unsigned short h) {
    return __uint_as_float(((unsigned)h) << 16);
}

// ---------------- prep: split features into bf16 hi/lo ----------------------
__global__ __launch_bounds__(256) void split_feat(
    const float* __restrict__ X, unsigned short* __restrict__ Xh,
    unsigned short* __restrict__ Xl, int n, int n_pad)
{
    size_t idx = ((size_t)blockIdx.x * 256 + threadIdx.x) * 4;
    if (idx >= (size_t)n_pad * K_FEATS) return;
    int row = (int)(idx >> 7);
    float4 v = make_float4(0.f, 0.f, 0.f, 0.f);
    if (row < n) v = *(const float4*)(X + idx);
    float f[4] = {v.x, v.y, v.z, v.w};
    union { ushort4 q; unsigned short u[4]; } H, L;
#pragma unroll
    for (int j = 0; j < 4; j++) {
        H.u[j] = bf16_rne(f[j]);
        L.u[j] = bf16_rne(f[j] - bf16_f(H.u[j]));
    }
    *(ushort4*)(Xh + idx) = H.q;
    *(ushort4*)(Xl + idx) = L.q;
}

// ---------------- prep: transpose+split all three W in one dispatch ---------
__global__ __launch_bounds__(256) void split_w3(
    const float* __restrict__ W0, const float* __restrict__ W1,
    const float* __restrict__ W2,
    unsigned short* __restrict__ W0th, unsigned short* __restrict__ W0tl,
    unsigned short* __restrict__ W1th, unsigned short* __restrict__ W1tl,
    unsigned short* __restrict__ W2th, unsigned short* __restrict__ W2tl)
{
    int e = blockIdx.x * 256 + threadIdx.x;
    const float* W;
    unsigned short *Wh, *Wl;
    int NC, idx;
    if (e < 16384)      { W = W0; Wh = W0th; Wl = W0tl; NC = 128; idx = e; }
    else if (e < 32768) { W = W1; Wh = W1th; Wl = W1tl; NC = 128; idx = e - 16384; }
    else if (e < 40960) { W = W2; Wh = W2th; Wl = W2tl; NC = 64;  idx = e - 32768; }
    else return;
    int c = idx >> 7, k = idx & 127;
    float w = W[k * NC + c];
    unsigned short h = bf16_rne(w);
    Wh[idx] = h;
    Wl[idx] = bf16_rne(w - bf16_f(h));
}

// ---------------- coarse count: 256-bin LDS hist per chunk -------------------
__global__ __launch_bounds__(256) void bucket_count(
    const int* __restrict__ src, const int* __restrict__ dst,
    int* __restrict__ partialS, int* __restrict__ partialD,
    int ne, int chunkA, int C, int NB)
{
    __shared__ int h[256];
    int c = blockIdx.x, t = threadIdx.x;
    const int* key = blockIdx.y ? dst : src;
    int* part = blockIdx.y ? partialD : partialS;
    if (t < NB) h[t] = 0;
    __syncthreads();
    int e0 = c * chunkA, e1 = min(ne, e0 + chunkA);
    for (int e = e0 + t; e < e1; e += 256)
        atomicAdd(&h[key[e] >> RBSHIFT], 1);
    __syncthreads();
    for (int i = t; i < NB; i += 256) part[i * C + c] = h[i];
}

__global__ __launch_bounds__(256) void bucket_prefix(
    int* __restrict__ partialS, int* __restrict__ partialD,
    int* __restrict__ totS, int* __restrict__ totD, int C, int NB)
{
    __shared__ int sh[256];
    int b = blockIdx.x, t = threadIdx.x;
    int* part = blockIdx.y ? partialD : partialS;
    int* tot = blockIdx.y ? totD : totS;
    int v = (t < C) ? part[b * C + t] : 0;
    sh[t] = v;
    __syncthreads();
    for (int off = 1; off < 256; off <<= 1) {
        int x = (t >= off) ? sh[t - off] : 0;
        __syncthreads();
        sh[t] += x;
        __syncthreads();
    }
    if (t < C) part[b * C + t] = sh[t] - v;
    if (t == 255) tot[b] = sh[255];
}

__global__ __launch_bounds__(256) void bucket_off_kernel(
    const int* __restrict__ totS, const int* __restrict__ totD,
    int* __restrict__ offS, int* __restrict__ offD,
    int* __restrict__ row_off, int NB, int n, int ne)
{
    __shared__ int sh[256];
    int t = threadIdx.x;
    if (t == 0) row_off[n] = ne;
    for (int a = 0; a < 2; a++) {
        const int* tot = a ? totD : totS;
        int* boff = a ? offD : offS;
        int v = (t < NB) ? tot[t] : 0;
        sh[t] = v;
        __syncthreads();
        for (int off = 1; off < 256; off <<= 1) {
            int x = (t >= off) ? sh[t - off] : 0;
            __syncthreads();
            sh[t] += x;
            __syncthreads();
        }
        if (t < NB) boff[t] = sh[t] - v;
        if (t == NB - 1) boff[NB] = sh[t];
        __syncthreads();
    }
}

__global__ __launch_bounds__(256) void bucket_scatter(
    const int* __restrict__ src, const int* __restrict__ dst,
    const int* __restrict__ partialS, const int* __restrict__ partialD,
    const int* __restrict__ offS, const int* __restrict__ offD,
    int* __restrict__ src_bkt, int2* __restrict__ edge_bkt,
    int ne, int chunkA, int C, int NB)
{
    __shared__ int cur[256];
    int c = blockIdx.x, a = blockIdx.y, t = threadIdx.x;
    const int* part = a ? partialD : partialS;
    const int* boff = a ? offD : offS;
    if (t < NB) cur[t] = boff[t] + part[t * C + c];
    __syncthreads();
    int e0 = c * chunkA, e1 = min(ne, e0 + chunkA);
    if (a) {
        for (int e = e0 + t; e < e1; e += 256) {
            int d = dst[e];
            int pos = atomicAdd(&cur[d >> RBSHIFT], 1);
            edge_bkt[pos] = make_int2(d, src[e]);
        }
    } else {
        for (int e = e0 + t; e < e1; e += 256) {
            int s = src[e];
            int pos = atomicAdd(&cur[s >> RBSHIFT], 1);
            src_bkt[pos] = s;
        }
    }
}

// ------- fine count dst: hist + in-LDS scan -> row_off + norm_dst -----------
__global__ __launch_bounds__(256) void fine_count_dst(
    const int2* __restrict__ edge_bkt, const int* __restrict__ offD,
    int* __restrict__ row_off, float* __restrict__ norm_dst, int n)
{
    __shared__ int h[RB];
    __shared__ int ps[256];
    int b = blockIdx.x, t = threadIdx.x;
    for (int i = t; i < RB; i += 256) h[i] = 0;
    __syncthreads();
    int lo = b << RBSHIFT;
    int ebase = offD[b];
    int e1 = offD[b + 1];
    for (int e = ebase + t; e < e1; e += 256)
        atomicAdd(&h[edge_bkt[e].x - lo], 1);
    __syncthreads();
    int v0 = h[2 * t], v1 = h[2 * t + 1];
    ps[t] = v0 + v1;
    __syncthreads();
    for (int off = 1; off < 256; off <<= 1) {
        int x = (t >= off) ? ps[t - off] : 0;
        __syncthreads();
        ps[t] += x;
        __syncthreads();
    }
    int excl = ps[t] - (v0 + v1) + ebase;
    int g0 = lo + 2 * t, g1 = g0 + 1;
    if (g0 < n) { row_off[g0] = excl;      norm_dst[g0] = rsqrtf((float)max(v0, 1)); }
    if (g1 < n) { row_off[g1] = excl + v0; norm_dst[g1] = rsqrtf((float)max(v1, 1)); }
}

__global__ __launch_bounds__(256) void fine_count_src(
    const int* __restrict__ src_bkt, const int* __restrict__ offS,
    float* __restrict__ norm_src, int n)
{
    __shared__ int h[RB];
    int b = blockIdx.x, t = threadIdx.x;
    for (int i = t; i < RB; i += 256) h[i] = 0;
    __syncthreads();
    int lo = b << RBSHIFT;
    int e1 = offS[b + 1];
    for (int e = offS[b] + t; e < e1; e += 256)
        atomicAdd(&h[src_bkt[e] - lo], 1);
    __syncthreads();
    for (int i = t; i < RB; i += 256) {
        int g = lo + i;
        if (g < n) norm_src[g] = rsqrtf((float)max(h[i], 1));
    }
}

__global__ __launch_bounds__(256) void fine_scatter(
    const int2* __restrict__ edge_bkt, const int* __restrict__ offD,
    const int* __restrict__ row_off, int* __restrict__ csr, int n)
{
    __shared__ int cur[RB];
    int b = blockIdx.x, t = threadIdx.x;
    int lo = b << RBSHIFT;
    for (int i = t; i < RB; i += 256) {
        int g = lo + i;
        cur[i] = (g < n) ? row_off[g] : 0;
    }
    __syncthreads();
    int e1 = offD[b + 1];
    for (int e = offD[b] + t; e < e1; e += 256) {
        int2 p = edge_bkt[e];
        int pos = atomicAdd(&cur[p.x - lo], 1);
        csr[pos] = p.y;
    }
}

// ---------------- MFMA GEMM: out = scale ⊙ (X @ W), bf16 hi/lo split --------
// X hi/lo bf16 [n_pad][128] row-major (direct global); W hi/lo bf16 transposed
// [NCOL][128], staged per-k-slice in LDS (bank-rotated pitch, ds_read_b128).
// A-frag A[m=lane&15][k=q*8+j]; B-frag B[k=q*8+j][n=lane&15];
// C/D: col=lane&15, row=q*4+reg  (m89/m120-verified layouts)
template <int NCOL, bool HALF_OUT>
__global__ __launch_bounds__(256) void gemm_mfma(
    const unsigned short* __restrict__ Xh, const unsigned short* __restrict__ Xl,
    const unsigned short* __restrict__ Wth, const unsigned short* __restrict__ Wtl,
    const float* __restrict__ scale, void* __restrict__ outv, int n)
{
    constexpr int CT = NCOL / 16;
    constexpr int QP = NCOL * 8 + 8;   // q-section pitch (shorts): +16B bank rotation
    __shared__ unsigned short WsH[4 * QP];
    __shared__ unsigned short WsL[4 * QP];

    int t = threadIdx.x;
    int w = t >> 6;
    int lane = t & 63;
    int m = lane & 15;
    int q = lane >> 4;
    int r0 = blockIdx.x * 128 + w * 32;

    f32x4 acc[2][CT];
#pragma unroll
    for (int i = 0; i < 2; i++)
#pragma unroll
        for (int j = 0; j < CT; j++) acc[i][j] = (f32x4){0.f, 0.f, 0.f, 0.f};

    size_t aoff0 = (size_t)(r0 + m) * K_FEATS + q * 8;
    size_t aoff1 = aoff0 + (size_t)16 * K_FEATS;

    for (int k0 = 0; k0 < K_FEATS; k0 += 32) {
        // stage W k-slice: Ws[j][col][0..7] = Wt[col][k0+j*8 .. +7]
        if (t < NCOL * 2) {
            int col = t & (NCOL - 1);
            int half = t / NCOL;
            const unsigned short* Wsrc = half ? Wtl : Wth;
            unsigned short* Wdst = half ? WsL : WsH;
#pragma unroll
            for (int j = 0; j < 4; j++) {
                bf16x8 v = *(const bf16x8*)(Wsrc + (size_t)col * K_FEATS + k0 + j * 8);
                *(bf16x8*)(Wdst + j * QP + col * 8) = v;
            }
        }
        __syncthreads();

        bf16x8 a0h = *(const bf16x8*)(Xh + aoff0 + k0);
        bf16x8 a0l = *(const bf16x8*)(Xl + aoff0 + k0);
        bf16x8 a1h = *(const bf16x8*)(Xh + aoff1 + k0);
        bf16x8 a1l = *(const bf16x8*)(Xl + aoff1 + k0);
#pragma unroll
        for (int ct = 0; ct < CT; ct++) {
            int wb = q * QP + (ct * 16 + m) * 8;
            bf16x8 bh = *(const bf16x8*)(WsH + wb);
            bf16x8 bl = *(const bf16x8*)(WsL + wb);
            acc[0][ct] = __builtin_amdgcn_mfma_f32_16x16x32_bf16(a0h, bh, acc[0][ct], 0, 0, 0);
            acc[0][ct] = __builtin_amdgcn_mfma_f32_16x16x32_bf16(a0l, bh, acc[0][ct], 0, 0, 0);
            acc[0][ct] = __builtin_amdgcn_mfma_f32_16x16x32_bf16(a0h, bl, acc[0][ct], 0, 0, 0);
            acc[1][ct] = __builtin_amdgcn_mfma_f32_16x16x32_bf16(a1h, bh, acc[1][ct], 0, 0, 0);
            acc[1][ct] = __builtin_amdgcn_mfma_f32_16x16x32_bf16(a1l, bh, acc[1][ct], 0, 0, 0);
            acc[1][ct] = __builtin_amdgcn_mfma_f32_16x16x32_bf16(a1h, bl, acc[1][ct], 0, 0, 0);
        }
        __syncthreads();
    }

#pragma unroll
    for (int rt = 0; rt < 2; rt++) {
        int rb = r0 + rt * 16 + q * 4;
#pragma unroll
        for (int reg = 0; reg < 4; reg++) {
            int row = rb + reg;
            if (row < n) {
                float s = scale[row];
#pragma unroll
                for (int ct = 0; ct < CT; ct++) {
                    float v = acc[rt][ct][reg] * s;
                    size_t o = (size_t)row * NCOL + ct * 16 + m;
                    if (HALF_OUT) ((__half*)outv)[o] = __float2half(v);
                    else ((float*)outv)[o] = v;
                }
            }
        }
    }
}

// ---------------- fp16-gather aggregation (128 feats) -> bf16 hi/lo out -----
// 16-lane teams, 8 fp16 feats/lane, 8 edges in flight (MLP)
template <bool RELU>
__global__ __launch_bounds__(256) void aggregate4h(
    const __half* __restrict__ Tm, const int* __restrict__ row_off,
    const int* __restrict__ csr, const float* __restrict__ ndst,
    const float* __restrict__ bias, unsigned short* __restrict__ Oh,
    unsigned short* __restrict__ Ol, int n)
{
    int lane = threadIdx.x & 15;
    int team = threadIdx.x >> 4;
    int fb = lane * 8;
    float b[8];
    *(float4*)&b[0] = *(const float4*)(bias + fb);
    *(float4*)&b[4] = *(const float4*)(bias + fb + 4);
    int stride = gridDim.x * 16;
    for (int v = blockIdx.x * 16 + team; v < n; v += stride) {
        int s = row_off[v], e = row_off[v + 1];
        float nd = ndst[v];
        float a[8] = {};
        int i = s;
        for (; i + 8 <= e; i += 8) {
            union { uint4 q; __half h[8]; } U[8];
            int u[8];
#pragma unroll
            for (int j = 0; j < 8; j++) u[j] = csr[i + j];
#pragma unroll
            for (int j = 0; j < 8; j++)
                U[j].q = *(const uint4*)(Tm + (size_t)u[j] * 128 + fb);
#pragma unroll
            for (int j = 0; j < 8; j++)
#pragma unroll
                for (int k = 0; k < 8; k++) a[k] += __half2float(U[j].h[k]);
        }
        for (; i < e; i++) {
            int u = csr[i];
            union { uint4 q; __half h[8]; } U;
            U.q = *(const uint4*)(Tm + (size_t)u * 128 + fb);
#pragma unroll
            for (int j = 0; j < 8; j++) a[j] += __half2float(U.h[j]);
        }
        union { uint4 q; unsigned short u[8]; } H, L;
#pragma unroll
        for (int j = 0; j < 8; j++) {
            float o = nd * a[j] + b[j];
            if (RELU) o = fmaxf(o, 0.f);
            H.u[j] = bf16_rne(o);
            L.u[j] = bf16_rne(o - bf16_f(H.u[j]));
        }
        *(uint4*)(Oh + (size_t)v * 128 + fb) = H.q;
        *(uint4*)(Ol + (size_t)v * 128 + fb) = L.q;
    }
}

// ---------------- fp32 aggregation (64 feats): 16-lane teams, 8-deep MLP ----
template <bool RELU>
__global__ __launch_bounds__(256) void aggregate2(
    const float* __restrict__ Tm, const int* __restrict__ row_off,
    const int* __restrict__ csr, const float* __restrict__ ndst,
    const float* __restrict__ bias, float* __restrict__ out, int n)
{
    int lane = threadIdx.x & 15;
    int team = threadIdx.x >> 4;
    int fb = lane * 4;
    float4 b = *(const float4*)(bias + fb);
    int stride = gridDim.x * 16;
    for (int v = blockIdx.x * 16 + team; v < n; v += stride) {
        int s = row_off[v], e = row_off[v + 1];
        float nd = ndst[v];
        float ax = 0.f, ay = 0.f, az = 0.f, aw = 0.f;
        int i = s;
        for (; i + 8 <= e; i += 8) {
            float4 T[8];
            int u[8];
#pragma unroll
            for (int j = 0; j < 8; j++) u[j] = csr[i + j];
#pragma unroll
            for (int j = 0; j < 8; j++)
                T[j] = *(const float4*)(Tm + (size_t)u[j] * 64 + fb);
#pragma unroll
            for (int j = 0; j < 8; j++) {
                ax += T[j].x; ay += T[j].y; az += T[j].z; aw += T[j].w;
            }
        }
        for (; i < e; i++) {
            int u = csr[i];
            float4 t0 = *(const float4*)(Tm + (size_t)u * 64 + fb);
            ax += t0.x; ay += t0.y; az += t0.z; aw += t0.w;
        }
        float4 o;
        o.x = nd * ax + b.x;
        o.y = nd * ay + b.y;
        o.z = nd * az + b.z;
        o.w = nd * aw + b.w;
        if (RELU) {
            o.x = fmaxf(o.x, 0.f); o.y = fmaxf(o.y, 0.f);
            o.z = fmaxf(o.z, 0.f); o.w = fmaxf(o.w, 0.f);
        }
        *(float4*)(out + (size_t)v * 64 + fb) = o;
    }
}

// ---------------- launch ----------------
extern "C" void kernel_launch(void* const* d_in, const int* in_sizes, int n_in,
                              void* d_out, int out_size, void* d_ws, size_t ws_size,
                              hipStream_t stream)
{
    const float* features = (const float*)d_in[0];
    const int* src = (const int*)d_in[1];
    const int* dst = (const int*)d_in[2];
    const float* W0 = (const float*)d_in[3];
    const float* b0 = (const float*)d_in[4];
    const float* W1 = (const float*)d_in[5];
    const float* b1 = (const float*)d_in[6];
    const float* W2 = (const float*)d_in[7];
    const float* b2 = (const float*)d_in[8];

    int n = in_sizes[0] / K_FEATS;  // 100000
    int ne = in_sizes[1];           // 1600000
    int n_pad = (n + 127) & ~127;   // 100096

    char* ws = (char*)d_ws;
    size_t off = 0;
    auto take = [&](size_t bytes) -> char* {
        char* p = ws + off;
        off = (off + bytes + 255) & ~(size_t)255;
        return p;
    };
    unsigned short* XBh = (unsigned short*)take((size_t)n_pad * 128 * 2);
    unsigned short* XBl = (unsigned short*)take((size_t)n_pad * 128 * 2);
    char* Tbuf = take((size_t)n_pad * 128 * 2);   // fp16 [n][128] or fp32 [n][64]
    int* csr = (int*)take((size_t)ne * 4);
    int2* edge_bkt = (int2*)take((size_t)ne * 8);
    int* src_bkt = (int*)take((size_t)ne * 4);
    int* row_off = (int*)take((size_t)(n + 1) * 4);
    float* norm_src = (float*)take((size_t)n * 4);
    float* norm_dst = (float*)take((size_t)n * 4);
    unsigned short* W0th = (unsigned short*)take(128 * 128 * 2);
    unsigned short* W0tl = (unsigned short*)take(128 * 128 * 2);
    unsigned short* W1th = (unsigned short*)take(128 * 128 * 2);
    unsigned short* W1tl = (unsigned short*)take(128 * 128 * 2);
    unsigned short* W2th = (unsigned short*)take(64 * 128 * 2);
    unsigned short* W2tl = (unsigned short*)take(64 * 128 * 2);

    int NB = (n + RB - 1) >> RBSHIFT;        // 196 (must be <= 256)
    int chunkA = 8192;
    int C = (ne + chunkA - 1) / chunkA;
    if (C > 256) { chunkA = (ne + 255) / 256; C = (ne + chunkA - 1) / chunkA; }

    int* partialS = (int*)take((size_t)NB * C * 4);
    int* partialD = (int*)take((size_t)NB * C * 4);
    int* totS = (int*)take((size_t)NB * 4);
    int* totD = (int*)take((size_t)NB * 4);
    int* offS = (int*)take((size_t)(NB + 1) * 4);
    int* offD = (int*)take((size_t)(NB + 1) * 4);

    // prep: feature + weight splits
    int fblocks = (int)(((size_t)n_pad * 128 / 4 + 255) / 256);
    split_feat<<<fblocks, 256, 0, stream>>>(features, XBh, XBl, n, n_pad);
    split_w3<<<160, 256, 0, stream>>>(W0, W1, W2, W0th, W0tl, W1th, W1tl, W2th, W2tl);

    // CSR build (two-level counting sort; row_off folded into fine_count_dst)
    bucket_count<<<dim3(C, 2), 256, 0, stream>>>(src, dst, partialS, partialD,
                                                 ne, chunkA, C, NB);
    bucket_prefix<<<dim3(NB, 2), 256, 0, stream>>>(partialS, partialD, totS, totD, C, NB);
    bucket_off_kernel<<<1, 256, 0, stream>>>(totS, totD, offS, offD, row_off, NB, n, ne);
    bucket_scatter<<<dim3(C, 2), 256, 0, stream>>>(src, dst, partialS, partialD,
                                                   offS, offD, src_bkt, edge_bkt,
                                                   ne, chunkA, C, NB);
    fine_count_dst<<<NB, 256, 0, stream>>>(edge_bkt, offD, row_off, norm_dst, n);
    fine_count_src<<<NB, 256, 0, stream>>>(src_bkt, offS, norm_src, n);
    fine_scatter<<<NB, 256, 0, stream>>>(edge_bkt, offD, row_off, csr, n);

    int gblocks = n_pad / 128;
    int ablocks = (n + 15) / 16;
    __half* Th = (__half*)Tbuf;
    float* T64 = (float*)Tbuf;

    // layer 0
    gemm_mfma<128, true><<<gblocks, 256, 0, stream>>>(XBh, XBl, W0th, W0tl,
                                                      norm_src, Th, n);
    aggregate4h<true><<<ablocks, 256, 0, stream>>>(Th, row_off, csr, norm_dst, b0,
                                                   XBh, XBl, n);
    // layer 1 (in-place ping: gemm consumed XB before agg rewrites it)
    gemm_mfma<128, true><<<gblocks, 256, 0, stream>>>(XBh, XBl, W1th, W1tl,
                                                      norm_src, Th, n);
    aggregate4h<true><<<ablocks, 256, 0, stream>>>(Th, row_off, csr, norm_dst, b1,
                                                   XBh, XBl, n);
    // layer 2 (NCOL=64, fp32 out, no relu)
    gemm_mfma<64, false><<<gblocks, 256, 0, stream>>>(XBh, XBl, W2th, W2tl,
                                                      norm_src, T64, n);
    aggregate2<false><<<ablocks, 256, 0, stream>>>(T64, row_off, csr, norm_dst, b2,
                                                   (float*)d_out, n);
}

// Round 8
// 427.240 us; speedup vs baseline: 2.1471x; 1.0948x over previous
//
#include <hip/hip_runtime.h>
#include <hip/hip_fp16.h>

#define K_FEATS 128
#define RBSHIFT 9
#define RB 512        // fine-bucket node range (pow2); NB = ceil(n/512) <= 256

typedef short bf16x8 __attribute__((ext_vector_type(8)));
typedef float f32x4 __attribute__((ext_vector_type(4)));

__device__ __forceinline__ unsigned short bf16_rne(float x) {
    unsigned u = __float_as_uint(x);
    unsigned r = (u + 0x7FFFu + ((u >> 16) & 1u)) >> 16;
    return (unsigned short)r;
}
__device__ __forceinline__ float bf16_f(unsigned short h) {
    return __uint_as_float(((unsigned)h) << 16);
}

// ---------------- prep: split features into bf16 hi/lo ----------------------
__global__ __launch_bounds__(256) void split_feat(
    const float* __restrict__ X, unsigned short* __restrict__ Xh,
    unsigned short* __restrict__ Xl, int n, int n_pad)
{
    size_t idx = ((size_t)blockIdx.x * 256 + threadIdx.x) * 4;
    if (idx >= (size_t)n_pad * K_FEATS) return;
    int row = (int)(idx >> 7);
    float4 v = make_float4(0.f, 0.f, 0.f, 0.f);
    if (row < n) v = *(const float4*)(X + idx);
    float f[4] = {v.x, v.y, v.z, v.w};
    union { ushort4 q; unsigned short u[4]; } H, L;
#pragma unroll
    for (int j = 0; j < 4; j++) {
        H.u[j] = bf16_rne(f[j]);
        L.u[j] = bf16_rne(f[j] - bf16_f(H.u[j]));
    }
    *(ushort4*)(Xh + idx) = H.q;
    *(ushort4*)(Xl + idx) = L.q;
}

// ---------------- prep: transpose+split all three W in one dispatch ---------
__global__ __launch_bounds__(256) void split_w3(
    const float* __restrict__ W0, const float* __restrict__ W1,
    const float* __restrict__ W2,
    unsigned short* __restrict__ W0th, unsigned short* __restrict__ W0tl,
    unsigned short* __restrict__ W1th, unsigned short* __restrict__ W1tl,
    unsigned short* __restrict__ W2th, unsigned short* __restrict__ W2tl)
{
    int e = blockIdx.x * 256 + threadIdx.x;
    const float* W;
    unsigned short *Wh, *Wl;
    int NC, idx;
    if (e < 16384)      { W = W0; Wh = W0th; Wl = W0tl; NC = 128; idx = e; }
    else if (e < 32768) { W = W1; Wh = W1th; Wl = W1tl; NC = 128; idx = e - 16384; }
    else if (e < 40960) { W = W2; Wh = W2th; Wl = W2tl; NC = 64;  idx = e - 32768; }
    else return;
    int c = idx >> 7, k = idx & 127;
    float w = W[k * NC + c];
    unsigned short h = bf16_rne(w);
    Wh[idx] = h;
    Wl[idx] = bf16_rne(w - bf16_f(h));
}

// ---------------- coarse count: 256-bin LDS hist per chunk -------------------
__global__ __launch_bounds__(256) void bucket_count(
    const int* __restrict__ src, const int* __restrict__ dst,
    int* __restrict__ partialS, int* __restrict__ partialD,
    int ne, int chunkA, int C, int NB)
{
    __shared__ int h[256];
    int c = blockIdx.x, t = threadIdx.x;
    const int* key = blockIdx.y ? dst : src;
    int* part = blockIdx.y ? partialD : partialS;
    if (t < NB) h[t] = 0;
    __syncthreads();
    int e0 = c * chunkA, e1 = min(ne, e0 + chunkA);
    for (int e = e0 + t; e < e1; e += 256)
        atomicAdd(&h[key[e] >> RBSHIFT], 1);
    __syncthreads();
    for (int i = t; i < NB; i += 256) part[i * C + c] = h[i];
}

__global__ __launch_bounds__(256) void bucket_prefix(
    int* __restrict__ partialS, int* __restrict__ partialD,
    int* __restrict__ totS, int* __restrict__ totD, int C, int NB)
{
    __shared__ int sh[256];
    int b = blockIdx.x, t = threadIdx.x;
    int* part = blockIdx.y ? partialD : partialS;
    int* tot = blockIdx.y ? totD : totS;
    int v = (t < C) ? part[b * C + t] : 0;
    sh[t] = v;
    __syncthreads();
    for (int off = 1; off < 256; off <<= 1) {
        int x = (t >= off) ? sh[t - off] : 0;
        __syncthreads();
        sh[t] += x;
        __syncthreads();
    }
    if (t < C) part[b * C + t] = sh[t] - v;
    if (t == 255) tot[b] = sh[255];
}

__global__ __launch_bounds__(256) void bucket_off_kernel(
    const int* __restrict__ totS, const int* __restrict__ totD,
    int* __restrict__ offS, int* __restrict__ offD,
    int* __restrict__ row_off, int NB, int n, int ne)
{
    __shared__ int sh[256];
    int t = threadIdx.x;
    if (t == 0) row_off[n] = ne;
    for (int a = 0; a < 2; a++) {
        const int* tot = a ? totD : totS;
        int* boff = a ? offD : offS;
        int v = (t < NB) ? tot[t] : 0;
        sh[t] = v;
        __syncthreads();
        for (int off = 1; off < 256; off <<= 1) {
            int x = (t >= off) ? sh[t - off] : 0;
            __syncthreads();
            sh[t] += x;
            __syncthreads();
        }
        if (t < NB) boff[t] = sh[t] - v;
        if (t == NB - 1) boff[NB] = sh[t];
        __syncthreads();
    }
}

// ------- coarse scatter (single pass, both arrays, packed records) ----------
// edge_bkt[pos] = (d&511)<<17 | src  (26 bits); src_bkt[pos] = src&511
__global__ __launch_bounds__(256) void bucket_scatter(
    const int* __restrict__ src, const int* __restrict__ dst,
    const int* __restrict__ partialS, const int* __restrict__ partialD,
    const int* __restrict__ offS, const int* __restrict__ offD,
    unsigned short* __restrict__ src_bkt, int* __restrict__ edge_bkt,
    int ne, int chunkA, int C, int NB)
{
    __shared__ int curS[256];
    __shared__ int curD[256];
    int c = blockIdx.x, t = threadIdx.x;
    if (t < NB) {
        curS[t] = offS[t] + partialS[t * C + c];
        curD[t] = offD[t] + partialD[t * C + c];
    }
    __syncthreads();
    int e0 = c * chunkA, e1 = min(ne, e0 + chunkA);
    for (int e = e0 + t; e < e1; e += 256) {
        int s = src[e];
        int d = dst[e];
        int posD = atomicAdd(&curD[d >> RBSHIFT], 1);
        edge_bkt[posD] = ((d & (RB - 1)) << 17) | s;
        int posS = atomicAdd(&curS[s >> RBSHIFT], 1);
        src_bkt[posS] = (unsigned short)(s & (RB - 1));
    }
}

// ------- fused fine pass: y=0 dst (hist+scan->row_off/norm_dst + scatter),
//         y=1 src (hist->norm_src) -------------------------------------------
__global__ __launch_bounds__(256) void fine_all(
    const int* __restrict__ edge_bkt, const unsigned short* __restrict__ src_bkt,
    const int* __restrict__ offD, const int* __restrict__ offS,
    int* __restrict__ row_off, float* __restrict__ norm_dst,
    float* __restrict__ norm_src, int* __restrict__ csr, int n)
{
    __shared__ int h[RB];
    __shared__ int ps[256];
    int b = blockIdx.x, t = threadIdx.x;
    int lo = b << RBSHIFT;
    for (int i = t; i < RB; i += 256) h[i] = 0;
    __syncthreads();
    if (blockIdx.y == 1) {
        int e1 = offS[b + 1];
        for (int e = offS[b] + t; e < e1; e += 256)
            atomicAdd(&h[src_bkt[e]], 1);
        __syncthreads();
        for (int i = t; i < RB; i += 256) {
            int g = lo + i;
            if (g < n) norm_src[g] = rsqrtf((float)max(h[i], 1));
        }
        return;
    }
    int ebase = offD[b];
    int e1 = offD[b + 1];
    for (int e = ebase + t; e < e1; e += 256)
        atomicAdd(&h[(unsigned)edge_bkt[e] >> 17], 1);
    __syncthreads();
    int v0 = h[2 * t], v1 = h[2 * t + 1];
    ps[t] = v0 + v1;
    __syncthreads();
    for (int off = 1; off < 256; off <<= 1) {
        int x = (t >= off) ? ps[t - off] : 0;
        __syncthreads();
        ps[t] += x;
        __syncthreads();
    }
    int excl = ps[t] - (v0 + v1) + ebase;
    int g0 = lo + 2 * t, g1 = g0 + 1;
    if (g0 < n) { row_off[g0] = excl;      norm_dst[g0] = rsqrtf((float)max(v0, 1)); }
    if (g1 < n) { row_off[g1] = excl + v0; norm_dst[g1] = rsqrtf((float)max(v1, 1)); }
    h[2 * t] = excl;          // cursors
    h[2 * t + 1] = excl + v0;
    __syncthreads();
    for (int e = ebase + t; e < e1; e += 256) {
        int p = edge_bkt[e];
        int pos = atomicAdd(&h[(unsigned)p >> 17], 1);
        csr[pos] = p & 0x1FFFF;
    }
}

// ---------------- MFMA GEMM: out = scale ⊙ (X @ W), bf16 hi/lo split --------
// Full W half staged in LDS once (XOR-swizzled, conflict-free), barrier-free
// K-loop. A-frags loaded up front; A-hi retained across both phases.
// A-frag A[m=lane&15][k=q*8+j]; B-frag B[k=q*8+j][n=lane&15];
// C/D: col=lane&15, row=q*4+reg  (m89/m120-verified layouts)
template <int NCOL, bool HALF_OUT>
__global__ __launch_bounds__(256) void gemm_mfma(
    const unsigned short* __restrict__ Xh, const unsigned short* __restrict__ Xl,
    const unsigned short* __restrict__ Wth, const unsigned short* __restrict__ Wtl,
    const float* __restrict__ scale, void* __restrict__ outv, int n)
{
    constexpr int CT = NCOL / 16;
    constexpr int CHUNKS = NCOL * 16;          // 16B chunks per half
    __shared__ unsigned short Ws[16 * NCOL * 8];  // [sec][col^(sec&7)][8]

    int t = threadIdx.x;
    int w = t >> 6, lane = t & 63, m = lane & 15, q = lane >> 4;
    int r0 = blockIdx.x * 128 + w * 32;

    f32x4 acc[2][CT];
#pragma unroll
    for (int i = 0; i < 2; i++)
#pragma unroll
        for (int j = 0; j < CT; j++) acc[i][j] = (f32x4){0.f, 0.f, 0.f, 0.f};

    size_t aoff0 = (size_t)(r0 + m) * K_FEATS + q * 8;
    size_t aoff1 = aoff0 + (size_t)16 * K_FEATS;

    // all A fragments up front (16 b128 global loads)
    bf16x8 ah[2][4], al[2][4];
#pragma unroll
    for (int k = 0; k < 4; k++) {
        ah[0][k] = *(const bf16x8*)(Xh + aoff0 + k * 32);
        ah[1][k] = *(const bf16x8*)(Xh + aoff1 + k * 32);
        al[0][k] = *(const bf16x8*)(Xl + aoff0 + k * 32);
        al[1][k] = *(const bf16x8*)(Xl + aoff1 + k * 32);
    }

    // stage W-hi
#pragma unroll
    for (int i = 0; i < CHUNKS / 256; i++) {
        int g = t + i * 256;
        int col = g >> 4, sec = g & 15;
        *(bf16x8*)(Ws + sec * NCOL * 8 + ((col ^ (sec & 7)) * 8)) =
            *(const bf16x8*)(Wth + g * 8);
    }
    __syncthreads();
    // phase 1: a_h*b_h + a_l*b_h
#pragma unroll
    for (int k = 0; k < 4; k++) {
        int sec = k * 4 + q;
#pragma unroll
        for (int ct = 0; ct < CT; ct++) {
            bf16x8 bh = *(const bf16x8*)(Ws + sec * NCOL * 8 +
                                         (((ct * 16 + m) ^ (sec & 7)) * 8));
            acc[0][ct] = __builtin_amdgcn_mfma_f32_16x16x32_bf16(ah[0][k], bh, acc[0][ct], 0, 0, 0);
            acc[0][ct] = __builtin_amdgcn_mfma_f32_16x16x32_bf16(al[0][k], bh, acc[0][ct], 0, 0, 0);
            acc[1][ct] = __builtin_amdgcn_mfma_f32_16x16x32_bf16(ah[1][k], bh, acc[1][ct], 0, 0, 0);
            acc[1][ct] = __builtin_amdgcn_mfma_f32_16x16x32_bf16(al[1][k], bh, acc[1][ct], 0, 0, 0);
        }
    }
    __syncthreads();
    // stage W-lo
#pragma unroll
    for (int i = 0; i < CHUNKS / 256; i++) {
        int g = t + i * 256;
        int col = g >> 4, sec = g & 15;
        *(bf16x8*)(Ws + sec * NCOL * 8 + ((col ^ (sec & 7)) * 8)) =
            *(const bf16x8*)(Wtl + g * 8);
    }
    __syncthreads();
    // phase 2: a_h*b_l
#pragma unroll
    for (int k = 0; k < 4; k++) {
        int sec = k * 4 + q;
#pragma unroll
        for (int ct = 0; ct < CT; ct++) {
            bf16x8 bl = *(const bf16x8*)(Ws + sec * NCOL * 8 +
                                         (((ct * 16 + m) ^ (sec & 7)) * 8));
            acc[0][ct] = __builtin_amdgcn_mfma_f32_16x16x32_bf16(ah[0][k], bl, acc[0][ct], 0, 0, 0);
            acc[1][ct] = __builtin_amdgcn_mfma_f32_16x16x32_bf16(ah[1][k], bl, acc[1][ct], 0, 0, 0);
        }
    }

#pragma unroll
    for (int rt = 0; rt < 2; rt++) {
        int rb = r0 + rt * 16 + q * 4;
#pragma unroll
        for (int reg = 0; reg < 4; reg++) {
            int row = rb + reg;
            if (row < n) {
                float s = scale[row];
#pragma unroll
                for (int ct = 0; ct < CT; ct++) {
                    float v = acc[rt][ct][reg] * s;
                    size_t o = (size_t)row * NCOL + ct * 16 + m;
                    if (HALF_OUT) ((__half*)outv)[o] = __float2half(v);
                    else ((float*)outv)[o] = v;
                }
            }
        }
    }
}

// ---------------- fp16-gather aggregation (128 feats) -> bf16 hi/lo out -----
// 16-lane teams, 8 fp16 feats/lane, 4 edges in flight (round-6 form: occ>ILP)
template <bool RELU>
__global__ __launch_bounds__(256) void aggregate4h(
    const __half* __restrict__ Tm, const int* __restrict__ row_off,
    const int* __restrict__ csr, const float* __restrict__ ndst,
    const float* __restrict__ bias, unsigned short* __restrict__ Oh,
    unsigned short* __restrict__ Ol, int n)
{
    int lane = threadIdx.x & 15;
    int team = threadIdx.x >> 4;
    int fb = lane * 8;
    float b[8];
    *(float4*)&b[0] = *(const float4*)(bias + fb);
    *(float4*)&b[4] = *(const float4*)(bias + fb + 4);
    int stride = gridDim.x * 16;
    for (int v = blockIdx.x * 16 + team; v < n; v += stride) {
        int s = row_off[v], e = row_off[v + 1];
        float nd = ndst[v];
        float a[8] = {};
        int i = s;
        for (; i + 4 <= e; i += 4) {
            int u0 = csr[i], u1 = csr[i + 1], u2 = csr[i + 2], u3 = csr[i + 3];
            union { uint4 q; __half h[8]; } U0, U1, U2, U3;
            U0.q = *(const uint4*)(Tm + (size_t)u0 * 128 + fb);
            U1.q = *(const uint4*)(Tm + (size_t)u1 * 128 + fb);
            U2.q = *(const uint4*)(Tm + (size_t)u2 * 128 + fb);
            U3.q = *(const uint4*)(Tm + (size_t)u3 * 128 + fb);
#pragma unroll
            for (int j = 0; j < 8; j++)
                a[j] += (__half2float(U0.h[j]) + __half2float(U1.h[j])) +
                        (__half2float(U2.h[j]) + __half2float(U3.h[j]));
        }
        for (; i < e; i++) {
            int u = csr[i];
            union { uint4 q; __half h[8]; } U;
            U.q = *(const uint4*)(Tm + (size_t)u * 128 + fb);
#pragma unroll
            for (int j = 0; j < 8; j++) a[j] += __half2float(U.h[j]);
        }
        union { uint4 q; unsigned short u[8]; } H, L;
#pragma unroll
        for (int j = 0; j < 8; j++) {
            float o = nd * a[j] + b[j];
            if (RELU) o = fmaxf(o, 0.f);
            H.u[j] = bf16_rne(o);
            L.u[j] = bf16_rne(o - bf16_f(H.u[j]));
        }
        *(uint4*)(Oh + (size_t)v * 128 + fb) = H.q;
        *(uint4*)(Ol + (size_t)v * 128 + fb) = L.q;
    }
}

// ---------------- fp32 aggregation (64 feats): 16-lane teams, 4-deep --------
template <bool RELU>
__global__ __launch_bounds__(256) void aggregate2(
    const float* __restrict__ Tm, const int* __restrict__ row_off,
    const int* __restrict__ csr, const float* __restrict__ ndst,
    const float* __restrict__ bias, float* __restrict__ out, int n)
{
    int lane = threadIdx.x & 15;
    int team = threadIdx.x >> 4;
    int fb = lane * 4;
    float4 b = *(const float4*)(bias + fb);
    int stride = gridDim.x * 16;
    for (int v = blockIdx.x * 16 + team; v < n; v += stride) {
        int s = row_off[v], e = row_off[v + 1];
        float nd = ndst[v];
        float ax = 0.f, ay = 0.f, az = 0.f, aw = 0.f;
        int i = s;
        for (; i + 4 <= e; i += 4) {
            int u0 = csr[i], u1 = csr[i + 1], u2 = csr[i + 2], u3 = csr[i + 3];
            float4 t0 = *(const float4*)(Tm + (size_t)u0 * 64 + fb);
            float4 t1 = *(const float4*)(Tm + (size_t)u1 * 64 + fb);
            float4 t2 = *(const float4*)(Tm + (size_t)u2 * 64 + fb);
            float4 t3 = *(const float4*)(Tm + (size_t)u3 * 64 + fb);
            ax += (t0.x + t1.x) + (t2.x + t3.x);
            ay += (t0.y + t1.y) + (t2.y + t3.y);
            az += (t0.z + t1.z) + (t2.z + t3.z);
            aw += (t0.w + t1.w) + (t2.w + t3.w);
        }
        for (; i < e; i++) {
            int u = csr[i];
            float4 t0 = *(const float4*)(Tm + (size_t)u * 64 + fb);
            ax += t0.x; ay += t0.y; az += t0.z; aw += t0.w;
        }
        float4 o;
        o.x = nd * ax + b.x;
        o.y = nd * ay + b.y;
        o.z = nd * az + b.z;
        o.w = nd * aw + b.w;
        if (RELU) {
            o.x = fmaxf(o.x, 0.f); o.y = fmaxf(o.y, 0.f);
            o.z = fmaxf(o.z, 0.f); o.w = fmaxf(o.w, 0.f);
        }
        *(float4*)(out + (size_t)v * 64 + fb) = o;
    }
}

// ---------------- launch ----------------
extern "C" void kernel_launch(void* const* d_in, const int* in_sizes, int n_in,
                              void* d_out, int out_size, void* d_ws, size_t ws_size,
                              hipStream_t stream)
{
    const float* features = (const float*)d_in[0];
    const int* src = (const int*)d_in[1];
    const int* dst = (const int*)d_in[2];
    const float* W0 = (const float*)d_in[3];
    const float* b0 = (const float*)d_in[4];
    const float* W1 = (const float*)d_in[5];
    const float* b1 = (const float*)d_in[6];
    const float* W2 = (const float*)d_in[7];
    const float* b2 = (const float*)d_in[8];

    int n = in_sizes[0] / K_FEATS;  // 100000
    int ne = in_sizes[1];           // 1600000
    int n_pad = (n + 127) & ~127;   // 100096

    char* ws = (char*)d_ws;
    size_t off = 0;
    auto take = [&](size_t bytes) -> char* {
        char* p = ws + off;
        off = (off + bytes + 255) & ~(size_t)255;
        return p;
    };
    unsigned short* XBh = (unsigned short*)take((size_t)n_pad * 128 * 2);
    unsigned short* XBl = (unsigned short*)take((size_t)n_pad * 128 * 2);
    char* Tbuf = take((size_t)n_pad * 128 * 2);   // fp16 [n][128] or fp32 [n][64]
    int* csr = (int*)take((size_t)ne * 4);
    int* edge_bkt = (int*)take((size_t)ne * 4);
    unsigned short* src_bkt = (unsigned short*)take((size_t)ne * 2);
    int* row_off = (int*)take((size_t)(n + 1) * 4);
    float* norm_src = (float*)take((size_t)n * 4);
    float* norm_dst = (float*)take((size_t)n * 4);
    unsigned short* W0th = (unsigned short*)take(128 * 128 * 2);
    unsigned short* W0tl = (unsigned short*)take(128 * 128 * 2);
    unsigned short* W1th = (unsigned short*)take(128 * 128 * 2);
    unsigned short* W1tl = (unsigned short*)take(128 * 128 * 2);
    unsigned short* W2th = (unsigned short*)take(64 * 128 * 2);
    unsigned short* W2tl = (unsigned short*)take(64 * 128 * 2);

    int NB = (n + RB - 1) >> RBSHIFT;        // 196 (must be <= 256)
    int chunkA = 8192;
    int C = (ne + chunkA - 1) / chunkA;
    if (C > 256) { chunkA = (ne + 255) / 256; C = (ne + chunkA - 1) / chunkA; }

    int* partialS = (int*)take((size_t)NB * C * 4);
    int* partialD = (int*)take((size_t)NB * C * 4);
    int* totS = (int*)take((size_t)NB * 4);
    int* totD = (int*)take((size_t)NB * 4);
    int* offS = (int*)take((size_t)(NB + 1) * 4);
    int* offD = (int*)take((size_t)(NB + 1) * 4);

    // prep: feature + weight splits
    int fblocks = (int)(((size_t)n_pad * 128 / 4 + 255) / 256);
    split_feat<<<fblocks, 256, 0, stream>>>(features, XBh, XBl, n, n_pad);
    split_w3<<<160, 256, 0, stream>>>(W0, W1, W2, W0th, W0tl, W1th, W1tl, W2th, W2tl);

    // CSR build (two-level counting sort, packed records, fused fine pass)
    bucket_count<<<dim3(C, 2), 256, 0, stream>>>(src, dst, partialS, partialD,
                                                 ne, chunkA, C, NB);
    bucket_prefix<<<dim3(NB, 2), 256, 0, stream>>>(partialS, partialD, totS, totD, C, NB);
    bucket_off_kernel<<<1, 256, 0, stream>>>(totS, totD, offS, offD, row_off, NB, n, ne);
    bucket_scatter<<<C, 256, 0, stream>>>(src, dst, partialS, partialD,
                                          offS, offD, src_bkt, edge_bkt,
                                          ne, chunkA, C, NB);
    fine_all<<<dim3(NB, 2), 256, 0, stream>>>(edge_bkt, src_bkt, offD, offS,
                                              row_off, norm_dst, norm_src, csr, n);

    int gblocks = n_pad / 128;
    int ablocks = (n + 15) / 16;
    __half* Th = (__half*)Tbuf;
    float* T64 = (float*)Tbuf;

    // layer 0
    gemm_mfma<128, true><<<gblocks, 256, 0, stream>>>(XBh, XBl, W0th, W0tl,
                                                      norm_src, Th, n);
    aggregate4h<true><<<ablocks, 256, 0, stream>>>(Th, row_off, csr, norm_dst, b0,
                                                   XBh, XBl, n);
    // layer 1 (in-place ping: gemm consumed XB before agg rewrites it)
    gemm_mfma<128, true><<<gblocks, 256, 0, stream>>>(XBh, XBl, W1th, W1tl,
                                                      norm_src, Th, n);
    aggregate4h<true><<<ablocks, 256, 0, stream>>>(Th, row_off, csr, norm_dst, b1,
                                                   XBh, XBl, n);
    // layer 2 (NCOL=64, fp32 out, no relu)
    gemm_mfma<64, false><<<gblocks, 256, 0, stream>>>(XBh, XBl, W2th, W2tl,
                                                      norm_src, T64, n);
    aggregate2<false><<<ablocks, 256, 0, stream>>>(T64, row_off, csr, norm_dst, b2,
                                                   (float*)d_out, n);
}